// Round 1
// baseline (1296.858 us; speedup 1.0000x reference)
//
#include <hip/hip_runtime.h>

#define NB 8
#define NWAY 16
#define NBASE 8000
#define FEAT 512
#define SEM 300
#define CAT (FEAT + SEM)  // 812

// ---------------- workspace layout (floats) ----------------
constexpr long OFF_H     = 0;                               // NB*NBASE*SEM   (19,200,000)
constexpr long OFF_MBW   = OFF_H + (long)NB * NBASE * SEM;  // NB*FEAT sums
constexpr long OFF_MH    = OFF_MBW + NB * FEAT;             // NB*SEM sums
constexpr long OFF_GV    = OFF_MH + NB * SEM;               // NB*FEAT
constexpr long OFF_GS    = OFF_GV + NB * FEAT;              // NB*SEM
constexpr long OFF_SSC   = OFF_GS + NB * SEM;               // NB*NWAY*SEM
constexpr long OFF_QTOT  = OFF_SSC + NB * NWAY * SEM;       // NB*NWAY*FEAT
constexpr long OFF_PSEM  = OFF_QTOT + NB * NWAY * FEAT;     // NB*SEM*NWAY
constexpr long OFF_PQ    = OFF_PSEM + NB * SEM * NWAY;      // NB*CAT*NWAY
constexpr long OFF_CONST = OFF_PQ + NB * CAT * NWAY;        // NB*NWAY
constexpr long OFF_PROBS = OFF_CONST + NB * NWAY;           // NB*NWAY*NBASE
constexpr long OFF_OV    = OFF_PROBS + (long)NB * NWAY * NBASE; // NB*NWAY*FEAT
constexpr long OFF_TMP   = OFF_OV + NB * NWAY * FEAT;       // NB*NWAY*FEAT
// total ~20.6M floats = 82.5 MB

// h = leaky_relu(base_seman @ map_w1 + b1)   M=64000, N=300, K=300
__global__ void k_hgemm(const float* __restrict__ X, const float* __restrict__ W1,
                        const float* __restrict__ b1, float* __restrict__ Hout) {
    __shared__ float As[32][65];  // [k][m]
    __shared__ float Bs[32][65];  // [k][n]
    int bn = blockIdx.x * 64;
    int bm = blockIdx.y * 64;
    int tid = threadIdx.x;
    int tx = tid % 16, ty = tid / 16;
    float acc[4][4] = {};
    for (int k0 = 0; k0 < SEM; k0 += 32) {
        for (int i = 0; i < 8; ++i) {
            int m = tid / 4;
            int kk = (tid % 4) * 8 + i;
            int gk = k0 + kk;
            float v = 0.f;
            if (gk < SEM) v = X[(long)(bm + m) * SEM + gk];
            As[kk][m] = v;
        }
        for (int i = 0; i < 8; ++i) {
            int n = tid % 64;
            int kk = (tid / 64) * 8 + i;
            int gk = k0 + kk, gn = bn + n;
            float v = 0.f;
            if (gk < SEM && gn < SEM) v = W1[(long)gk * SEM + gn];
            Bs[kk][n] = v;
        }
        __syncthreads();
        #pragma unroll
        for (int kk = 0; kk < 32; ++kk) {
            float a[4], b[4];
            #pragma unroll
            for (int i = 0; i < 4; ++i) a[i] = As[kk][ty * 4 + i];
            #pragma unroll
            for (int j = 0; j < 4; ++j) b[j] = Bs[kk][tx * 4 + j];
            #pragma unroll
            for (int i = 0; i < 4; ++i)
                #pragma unroll
                for (int j = 0; j < 4; ++j) acc[i][j] += a[i] * b[j];
        }
        __syncthreads();
    }
    for (int i = 0; i < 4; ++i) {
        int gm = bm + ty * 4 + i;
        for (int j = 0; j < 4; ++j) {
            int gn = bn + tx * 4 + j;
            if (gn < SEM) {
                float v = acc[i][j] + b1[gn];
                v = v > 0.f ? v : 0.1f * v;
                Hout[(long)gm * SEM + gn] = v;
            }
        }
    }
}

// column sums of base_weights over n  (grid: NB x 2 x 20, block 256)
__global__ void k_mean_bw(const float* __restrict__ bw, float* __restrict__ mbw) {
    int b = blockIdx.x;
    int f = blockIdx.y * 256 + threadIdx.x;
    int ch = blockIdx.z;
    const float* p = bw + (long)b * NBASE * FEAT + (long)ch * 400 * FEAT + f;
    float s = 0.f;
    for (int i = 0; i < 400; ++i) s += p[(long)i * FEAT];
    atomicAdd(&mbw[b * FEAT + f], s);
}

// column sums of h over n  (grid: NB x 20, block 320)
__global__ void k_mean_h(const float* __restrict__ h, float* __restrict__ mh) {
    int b = blockIdx.x, ch = blockIdx.y, s = threadIdx.x;
    if (s >= SEM) return;
    const float* p = h + (long)b * NBASE * SEM + (long)ch * 400 * SEM + s;
    float acc = 0.f;
    for (int i = 0; i < 400; ++i) acc += p[(long)i * SEM];
    atomicAdd(&mh[b * SEM + s], acc);
}

// support_seman calibration: full map_sem per row (grid NB*NWAY, block 320)
__global__ void k_ssc(const float* __restrict__ x, const float* __restrict__ w1,
                      const float* __restrict__ b1, const float* __restrict__ w2,
                      const float* __restrict__ b2, float* __restrict__ outp) {
    int row = blockIdx.x;
    int t = threadIdx.x;
    __shared__ float xr[SEM], hr[SEM];
    const float* xp = x + (long)row * SEM;
    if (t < SEM) xr[t] = xp[t];
    __syncthreads();
    if (t < SEM) {
        float a = b1[t];
        for (int k = 0; k < SEM; ++k) a += xr[k] * w1[(long)k * SEM + t];
        hr[t] = a > 0.f ? a : 0.1f * a;
    }
    __syncthreads();
    if (t < SEM) {
        float a = b2[t];
        for (int k = 0; k < SEM; ++k) a += hr[k] * w2[(long)k * SEM + t];
        outp[(long)row * SEM + t] = a;
    }
}

// gates from the (sum) accumulators (grid NB, block 256)
__global__ void k_gates(const float* __restrict__ mbw_sum, const float* __restrict__ mh_sum,
                        const float* __restrict__ w2, const float* __restrict__ b2,
                        const float* __restrict__ vfw, const float* __restrict__ vfb,
                        const float* __restrict__ sfw, const float* __restrict__ sfb,
                        float* __restrict__ gv, float* __restrict__ gs) {
    int b = blockIdx.x, t = threadIdx.x;
    __shared__ float avg[CAT];
    __shared__ float mh[SEM];
    const float invN = 1.0f / NBASE;
    for (int i = t; i < SEM; i += 256) mh[i] = mh_sum[b * SEM + i] * invN;
    for (int i = t; i < FEAT; i += 256) avg[i] = mbw_sum[b * FEAT + i] * invN;
    __syncthreads();
    for (int s = t; s < SEM; s += 256) {
        float a = b2[s];
        for (int k = 0; k < SEM; ++k) a += mh[k] * w2[(long)k * SEM + s];
        avg[FEAT + s] = a;
    }
    __syncthreads();
    for (int f = t; f < FEAT; f += 256) {
        float a = vfb[f];
        for (int c = 0; c < CAT; ++c) a += avg[c] * vfw[(long)c * FEAT + f];
        gv[b * FEAT + f] = 1.f + 1.f / (1.f + expf(-a));
    }
    for (int s = t; s < SEM; s += 256) {
        float a = sfb[s];
        for (int c = 0; c < CAT; ++c) a += avg[c] * sfw[(long)c * SEM + s];
        gs[b * SEM + s] = 1.f + 1.f / (1.f + expf(-a));
    }
}

// q_tot = support_feat @ w_qs + ssc @ w_qs_sem  (grid NB*NWAY, block 256)
__global__ void k_qtot(const float* __restrict__ sf, const float* __restrict__ ssc,
                       const float* __restrict__ wqs, const float* __restrict__ wqss,
                       float* __restrict__ qtot) {
    int row = blockIdx.x, t = threadIdx.x;
    __shared__ float fr[FEAT];
    __shared__ float sr[SEM];
    for (int i = t; i < FEAT; i += 256) fr[i] = sf[(long)row * FEAT + i];
    for (int i = t; i < SEM; i += 256) sr[i] = ssc[(long)row * SEM + i];
    __syncthreads();
    for (int col = t; col < FEAT; col += 256) {
        float a = 0.f;
        for (int k = 0; k < FEAT; ++k) a += fr[k] * wqs[(long)k * FEAT + col];
        for (int k = 0; k < SEM; ++k) a += sr[k] * wqss[(long)k * FEAT + col];
        qtot[(long)row * FEAT + col] = a;
    }
}

// PQ rows 0..511 (gated vis proj of q) and Psem_g (gated sem proj)
// grid (NB, 13), block 256; LDS-staged q_tot[b]
__global__ void k_pq1(const float* __restrict__ qtot, const float* __restrict__ wks,
                      const float* __restrict__ wkss, const float* __restrict__ gv,
                      const float* __restrict__ gs, float* __restrict__ pq,
                      float* __restrict__ psem) {
    int b = blockIdx.x, tile = blockIdx.y;
    int t = threadIdx.x;
    __shared__ float q[NWAY][FEAT + 1];
    for (int i = t; i < NWAY * FEAT; i += 256) q[i / FEAT][i % FEAT] = qtot[(long)b * NWAY * FEAT + i];
    __syncthreads();
    for (int item = t; item < 64 * NWAY; item += 256) {
        int cr = tile * 64 + item / NWAY;
        int w = item % NWAY;
        if (cr >= CAT) continue;
        const float* wrow;
        float g;
        if (cr < FEAT) { wrow = wks + (long)cr * FEAT; g = gv[b * FEAT + cr]; }
        else           { wrow = wkss + (long)(cr - FEAT) * FEAT; g = gs[b * SEM + (cr - FEAT)]; }
        float a = 0.f;
        for (int k = 0; k < FEAT; ++k) a += wrow[k] * q[w][k];
        a *= g;
        if (cr < FEAT) pq[((long)b * CAT + cr) * NWAY + w] = a;
        else           psem[((long)b * SEM + (cr - FEAT)) * NWAY + w] = a;
    }
}

// PQ rows 512..811 = W2^T-fold of Psem_g; cconst[b,w] = b2 . Psem_g[:,w]
// grid (NB, 5), block 256
__global__ void k_pq2(const float* __restrict__ psem, const float* __restrict__ w2,
                      const float* __restrict__ b2, float* __restrict__ pq,
                      float* __restrict__ cconst) {
    int b = blockIdx.x, tile = blockIdx.y;
    int t = threadIdx.x;
    __shared__ float ps[SEM][NWAY + 1];
    for (int i = t; i < SEM * NWAY; i += 256) ps[i / NWAY][i % NWAY] = psem[(long)b * SEM * NWAY + i];
    __syncthreads();
    for (int item = t; item < 64 * NWAY; item += 256) {
        int tr = tile * 64 + item / NWAY;
        int w = item % NWAY;
        if (tr >= SEM) continue;
        float a = 0.f;
        for (int s = 0; s < SEM; ++s) a += w2[(long)tr * SEM + s] * ps[s][w];
        pq[((long)b * CAT + FEAT + tr) * NWAY + w] = a;
    }
    if (tile == 0 && t < NWAY) {
        float a = 0.f;
        for (int s = 0; s < SEM; ++s) a += b2[s] * ps[s][t];
        cconst[b * NWAY + t] = a;
    }
}

// scores[b,w,n] = ([bw | h][n,:] . PQ[:,w] + const[b,w]) / temp
// per-batch 8000x16 GEMM with K=812; grid (63, NB), block 256
__global__ void k_scores(const float* __restrict__ bw, const float* __restrict__ h,
                         const float* __restrict__ pq, const float* __restrict__ cconst,
                         float* __restrict__ scores) {
    int b = blockIdx.y;
    int bm = blockIdx.x * 128;
    int tid = threadIdx.x;
    int tx = tid % 16, ty = tid / 16;
    __shared__ float As[32][129];
    __shared__ float Bs[32][16];
    float acc[8] = {};
    const float* bwb = bw + (long)b * NBASE * FEAT;
    const float* hb = h + (long)b * NBASE * SEM;
    const float* pqb = pq + (long)b * CAT * NWAY;
    for (int k0 = 0; k0 < CAT; k0 += 32) {
        for (int i = 0; i < 16; ++i) {
            int m = tid / 2;
            int kk = (tid % 2) * 16 + i;
            int gm = bm + m, gc = k0 + kk;
            float v = 0.f;
            if (gm < NBASE && gc < CAT)
                v = (gc < FEAT) ? bwb[(long)gm * FEAT + gc] : hb[(long)gm * SEM + (gc - FEAT)];
            As[kk][m] = v;
        }
        for (int i = 0; i < 2; ++i) {
            int e = tid * 2 + i;
            int kk = e / 16, w = e % 16;
            int gc = k0 + kk;
            Bs[kk][w] = (gc < CAT) ? pqb[(long)gc * NWAY + w] : 0.f;
        }
        __syncthreads();
        #pragma unroll
        for (int kk = 0; kk < 32; ++kk) {
            float bv = Bs[kk][tx];
            #pragma unroll
            for (int i = 0; i < 8; ++i) acc[i] += As[kk][ty * 8 + i] * bv;
        }
        __syncthreads();
    }
    const float invT = 0.04419417382415922f;  // 1/sqrt(512)
    float cadd = cconst[b * NWAY + tx];
    for (int i = 0; i < 8; ++i) {
        int n = bm + ty * 8 + i;
        if (n < NBASE) scores[((long)b * NWAY + tx) * NBASE + n] = (acc[i] + cadd) * invT;
    }
}

// row softmax over N=8000 (grid NB*NWAY, block 256)
__global__ void k_softmax(const float* __restrict__ scores, float* __restrict__ probs) {
    int row = blockIdx.x;
    int t = threadIdx.x;
    const float* p = scores + (long)row * NBASE;
    __shared__ float red[256];
    float mx = -1e30f;
    for (int i = t; i < NBASE; i += 256) mx = fmaxf(mx, p[i]);
    red[t] = mx;
    __syncthreads();
    for (int off = 128; off > 0; off >>= 1) {
        if (t < off) red[t] = fmaxf(red[t], red[t + off]);
        __syncthreads();
    }
    mx = red[0];
    __syncthreads();
    float sum = 0.f;
    for (int i = t; i < NBASE; i += 256) sum += expf(p[i] - mx);
    red[t] = sum;
    __syncthreads();
    for (int off = 128; off > 0; off >>= 1) {
        if (t < off) red[t] += red[t + off];
        __syncthreads();
    }
    float inv = 1.0f / red[0];
    for (int i = t; i < NBASE; i += 256) probs[(long)row * NBASE + i] = expf(p[i] - mx) * inv;
}

// ov[b,w,f] = sum_n probs[b,w,n] * bw[b,n,f]  (grid (NB,16) n-chunks of 500, block 256, 2 f each)
__global__ void k_ov(const float* __restrict__ probs, const float* __restrict__ bw,
                     float* __restrict__ ov) {
    int b = blockIdx.x, ch = blockIdx.y;
    int t = threadIdx.x;
    __shared__ float pr[NWAY][500];
    for (int i = t; i < NWAY * 500; i += 256) {
        int w = i / 500, j = i % 500;
        pr[w][j] = probs[((long)b * NWAY + w) * NBASE + (long)ch * 500 + j];
    }
    __syncthreads();
    float acc0[NWAY], acc1[NWAY];
    #pragma unroll
    for (int w = 0; w < NWAY; ++w) { acc0[w] = 0.f; acc1[w] = 0.f; }
    const float* bp = bw + ((long)b * NBASE + (long)ch * 500) * FEAT + t;
    for (int j = 0; j < 500; ++j) {
        float v0 = bp[(long)j * FEAT];
        float v1 = bp[(long)j * FEAT + 256];
        #pragma unroll
        for (int w = 0; w < NWAY; ++w) {
            acc0[w] += pr[w][j] * v0;
            acc1[w] += pr[w][j] * v1;
        }
    }
    for (int w = 0; w < NWAY; ++w) {
        atomicAdd(&ov[((long)b * NWAY + w) * FEAT + t], acc0[w]);
        atomicAdd(&ov[((long)b * NWAY + w) * FEAT + t + 256], acc1[w]);
    }
}

// Out = A(128x512) @ Wm(512x512) [+ Res]  (grid 128 rows, block 256)
__global__ void k_small_gemm(const float* __restrict__ A, const float* __restrict__ Wm,
                             const float* __restrict__ Res, float* __restrict__ Out) {
    int row = blockIdx.x, t = threadIdx.x;
    __shared__ float ar[FEAT];
    for (int i = t; i < FEAT; i += 256) ar[i] = A[(long)row * FEAT + i];
    __syncthreads();
    for (int col = t; col < FEAT; col += 256) {
        float a = 0.f;
        for (int k = 0; k < FEAT; ++k) a += ar[k] * Wm[(long)k * FEAT + col];
        if (Res) a += Res[(long)row * FEAT + col];
        Out[(long)row * FEAT + col] = a;
    }
}

extern "C" void kernel_launch(void* const* d_in, const int* in_sizes, int n_in,
                              void* d_out, int out_size, void* d_ws, size_t ws_size,
                              hipStream_t stream) {
    (void)in_sizes; (void)n_in; (void)out_size; (void)ws_size;
    const float* sf   = (const float*)d_in[0];
    const float* bw   = (const float*)d_in[1];
    const float* ssm  = (const float*)d_in[2];
    const float* bsm  = (const float*)d_in[3];
    const float* mw1  = (const float*)d_in[4];
    const float* mb1  = (const float*)d_in[5];
    const float* mw2  = (const float*)d_in[6];
    const float* mb2  = (const float*)d_in[7];
    const float* vfw  = (const float*)d_in[8];
    const float* vfb  = (const float*)d_in[9];
    const float* sfw  = (const float*)d_in[10];
    const float* sfb  = (const float*)d_in[11];
    const float* wqs  = (const float*)d_in[12];
    const float* wks  = (const float*)d_in[13];
    const float* wvs  = (const float*)d_in[14];
    const float* wqss = (const float*)d_in[15];
    const float* wkss = (const float*)d_in[16];
    const float* fcw  = (const float*)d_in[17];

    float* ws = (float*)d_ws;
    float* out = (float*)d_out;
    float* scores = out + NB * NWAY * FEAT;  // d_out = [out | attn_score]

    float* h      = ws + OFF_H;
    float* mbw    = ws + OFF_MBW;
    float* mh     = ws + OFF_MH;
    float* gv     = ws + OFF_GV;
    float* gs     = ws + OFF_GS;
    float* ssc    = ws + OFF_SSC;
    float* qtot   = ws + OFF_QTOT;
    float* psem   = ws + OFF_PSEM;
    float* pq     = ws + OFF_PQ;
    float* cconst = ws + OFF_CONST;
    float* probs  = ws + OFF_PROBS;
    float* ov     = ws + OFF_OV;
    float* tmp    = ws + OFF_TMP;

    // zero the accumulators (ws is poisoned 0xAA before every launch)
    hipMemsetAsync(mbw, 0, (NB * FEAT + NB * SEM) * sizeof(float), stream);
    hipMemsetAsync(ov, 0, NB * NWAY * FEAT * sizeof(float), stream);

    k_hgemm<<<dim3(5, 1000), 256, 0, stream>>>(bsm, mw1, mb1, h);
    k_mean_bw<<<dim3(NB, 2, 20), 256, 0, stream>>>(bw, mbw);
    k_ssc<<<NB * NWAY, 320, 0, stream>>>(ssm, mw1, mb1, mw2, mb2, ssc);
    k_mean_h<<<dim3(NB, 20), 320, 0, stream>>>(h, mh);
    k_gates<<<NB, 256, 0, stream>>>(mbw, mh, mw2, mb2, vfw, vfb, sfw, sfb, gv, gs);
    k_qtot<<<NB * NWAY, 256, 0, stream>>>(sf, ssc, wqs, wqss, qtot);
    k_pq1<<<dim3(NB, 13), 256, 0, stream>>>(qtot, wks, wkss, gv, gs, pq, psem);
    k_pq2<<<dim3(NB, 5), 256, 0, stream>>>(psem, mw2, mb2, pq, cconst);
    k_scores<<<dim3(63, NB), 256, 0, stream>>>(bw, h, pq, cconst, scores);
    k_softmax<<<NB * NWAY, 256, 0, stream>>>(scores, probs);
    k_ov<<<dim3(NB, 16), 256, 0, stream>>>(probs, bw, ov);
    k_small_gemm<<<NB * NWAY, 256, 0, stream>>>(ov, wvs, nullptr, tmp);
    k_small_gemm<<<NB * NWAY, 256, 0, stream>>>(tmp, fcw, sf, out);

    (void)wvs;
}

// Round 2
// 916.025 us; speedup vs baseline: 1.4157x; 1.4157x over previous
//
#include <hip/hip_runtime.h>

#define NB 8
#define NWAY 16
#define NBASE 8000
#define FEAT 512
#define SEM 300
#define CAT (FEAT + SEM)  // 812

typedef __attribute__((ext_vector_type(8))) short bf16x8;
typedef __attribute__((ext_vector_type(4))) float f32x4;
typedef __attribute__((ext_vector_type(4))) unsigned short us4;
typedef __attribute__((ext_vector_type(2))) unsigned short us2;

__device__ __forceinline__ unsigned short f2bf(float x) {
    union { float f; unsigned int u; } v; v.f = x;
    unsigned int r = v.u + 0x7FFFu + ((v.u >> 16) & 1u);
    return (unsigned short)(r >> 16);
}
__device__ __forceinline__ float bf2f(unsigned short u) {
    union { unsigned int u; float f; } v; v.u = ((unsigned int)u) << 16;
    return v.f;
}

// ---- workspace byte offsets ----
// bwh    @ 0           : 8*8000*512*2  = 65,536,000
// h      @ 65536000    : 8*8000*300*2  = 38,400,000
// w1t    @ 103936000   : 320*320*2     = 204,800
// pqt    @ 104140800   : 8*16*840*2    = 215,040
// probsb @ 104355840   : 8*16*8000*2   = 2,048,000
// floats from 106403840 (see kernel_launch)

// fp32->bf16 conversion of base_weights + fused column sums (replaces k_mean_bw)
__global__ void k_cvt_bw(const float* __restrict__ bw, unsigned short* __restrict__ bwh,
                         float* __restrict__ mbw) {
    int b = blockIdx.x, ch = blockIdx.y;  // 50 chunks of 160 rows
    int t = threadIdx.x;
    int cg = t & 127;   // float4 column group (4 cols)
    int rs = t >> 7;    // 0/1
    long base = ((long)b * NBASE + (long)ch * 160) * FEAT;
    float s0 = 0.f, s1 = 0.f, s2 = 0.f, s3 = 0.f;
    for (int r = rs; r < 160; r += 2) {
        float4 v = *(const float4*)(bw + base + (long)r * FEAT + cg * 4);
        us4 u; u.x = f2bf(v.x); u.y = f2bf(v.y); u.z = f2bf(v.z); u.w = f2bf(v.w);
        *(us4*)(bwh + base + (long)r * FEAT + cg * 4) = u;
        s0 += v.x; s1 += v.y; s2 += v.z; s3 += v.w;
    }
    atomicAdd(&mbw[b * FEAT + cg * 4 + 0], s0);
    atomicAdd(&mbw[b * FEAT + cg * 4 + 1], s1);
    atomicAdd(&mbw[b * FEAT + cg * 4 + 2], s2);
    atomicAdd(&mbw[b * FEAT + cg * 4 + 3], s3);
}

// W1^T bf16, padded to 320x320 with zeros
__global__ void k_prep_w1t(const float* __restrict__ w1, unsigned short* __restrict__ w1t) {
    int n = blockIdx.x;   // 0..319 (output dim)
    int k = threadIdx.x;  // 0..319 (input dim)
    float v = (n < SEM && k < SEM) ? w1[(long)k * SEM + n] : 0.f;
    w1t[(long)n * 320 + k] = f2bf(v);
}

// h = leaky_relu(bsm @ W1 + b1), bf16 MFMA.  M=64000 (BM=64/block), N=320, K=320
__global__ __launch_bounds__(256) void k_hgemm_mfma(const float* __restrict__ X,
        const unsigned short* __restrict__ W1T, const float* __restrict__ b1,
        unsigned short* __restrict__ H) {
    __shared__ unsigned short As[64][72];    // [m][k], +8 pad -> 2-way-free banks
    __shared__ unsigned short Bs[320][72];   // [n][k]
    const int bm = blockIdx.x * 64;
    const int t = threadIdx.x;
    const int wv = t >> 6, lane = t & 63;
    const int m16 = lane & 15, q = lane >> 4;
    f32x4 acc[4][5];
    #pragma unroll
    for (int i = 0; i < 4; ++i)
        #pragma unroll
        for (int j = 0; j < 5; ++j) acc[i][j] = (f32x4){0.f, 0.f, 0.f, 0.f};
    for (int ks = 0; ks < 5; ++ks) {
        const int k0 = ks * 64;
        #pragma unroll
        for (int it = 0; it < 4; ++it) {   // A: 64 rows x 16 chunks of 4 floats
            int c = t + it * 256;
            int row = c >> 4, j = c & 15;
            int gk = k0 + j * 4;
            float4 v = make_float4(0.f, 0.f, 0.f, 0.f);
            if (gk < SEM) v = *(const float4*)(X + (long)(bm + row) * SEM + gk);
            us4 u; u.x = f2bf(v.x); u.y = f2bf(v.y); u.z = f2bf(v.z); u.w = f2bf(v.w);
            *(us4*)(&As[row][j * 4]) = u;
        }
        #pragma unroll
        for (int it = 0; it < 10; ++it) {  // B: 320 rows x 8 chunks of 8 bf16
            int c = t + it * 256;
            int n = c >> 3, j = c & 7;
            int4 v = *(const int4*)(W1T + (long)n * 320 + k0 + j * 8);
            *(int4*)(&Bs[n][j * 8]) = v;
        }
        __syncthreads();
        #pragma unroll
        for (int kc = 0; kc < 64; kc += 32) {
            bf16x8 a[4], bb[5];
            #pragma unroll
            for (int rt = 0; rt < 4; ++rt)
                a[rt] = *(const bf16x8*)(&As[rt * 16 + m16][kc + q * 8]);
            #pragma unroll
            for (int ct = 0; ct < 5; ++ct)
                bb[ct] = *(const bf16x8*)(&Bs[(wv * 5 + ct) * 16 + m16][kc + q * 8]);
            #pragma unroll
            for (int rt = 0; rt < 4; ++rt)
                #pragma unroll
                for (int ct = 0; ct < 5; ++ct)
                    acc[rt][ct] = __builtin_amdgcn_mfma_f32_16x16x32_bf16(a[rt], bb[ct], acc[rt][ct], 0, 0, 0);
        }
        __syncthreads();
    }
    #pragma unroll
    for (int rt = 0; rt < 4; ++rt) {
        int row = bm + rt * 16 + q * 4;
        #pragma unroll
        for (int ct = 0; ct < 5; ++ct) {
            int col = (wv * 5 + ct) * 16 + m16;
            if (col < SEM) {
                float bias = b1[col];
                #pragma unroll
                for (int r = 0; r < 4; ++r) {
                    float v = acc[rt][ct][r] + bias;
                    v = v > 0.f ? v : 0.1f * v;
                    H[(long)(row + r) * SEM + col] = f2bf(v);
                }
            }
        }
    }
}

// column sums of bf16 h (grid NB x 20, block 320)
__global__ void k_mean_h_bf(const unsigned short* __restrict__ h, float* __restrict__ mh) {
    int b = blockIdx.x, ch = blockIdx.y, s = threadIdx.x;
    if (s >= SEM) return;
    const unsigned short* p = h + ((long)b * NBASE + (long)ch * 400) * SEM + s;
    float acc = 0.f;
    for (int i = 0; i < 400; ++i) acc += bf2f(p[(long)i * SEM]);
    atomicAdd(&mh[b * SEM + s], acc);
}

// support_seman calibration (fp32, tiny)
__global__ void k_ssc(const float* __restrict__ x, const float* __restrict__ w1,
                      const float* __restrict__ b1, const float* __restrict__ w2,
                      const float* __restrict__ b2, float* __restrict__ outp) {
    int row = blockIdx.x;
    int t = threadIdx.x;
    __shared__ float xr[SEM], hr[SEM];
    const float* xp = x + (long)row * SEM;
    if (t < SEM) xr[t] = xp[t];
    __syncthreads();
    if (t < SEM) {
        float a = b1[t];
        for (int k = 0; k < SEM; ++k) a += xr[k] * w1[(long)k * SEM + t];
        hr[t] = a > 0.f ? a : 0.1f * a;
    }
    __syncthreads();
    if (t < SEM) {
        float a = b2[t];
        for (int k = 0; k < SEM; ++k) a += hr[k] * w2[(long)k * SEM + t];
        outp[(long)row * SEM + t] = a;
    }
}

__global__ void k_gates(const float* __restrict__ mbw_sum, const float* __restrict__ mh_sum,
                        const float* __restrict__ w2, const float* __restrict__ b2,
                        const float* __restrict__ vfw, const float* __restrict__ vfb,
                        const float* __restrict__ sfw, const float* __restrict__ sfb,
                        float* __restrict__ gv, float* __restrict__ gs) {
    int b = blockIdx.x, t = threadIdx.x;
    __shared__ float avg[CAT];
    __shared__ float mh[SEM];
    const float invN = 1.0f / NBASE;
    for (int i = t; i < SEM; i += 256) mh[i] = mh_sum[b * SEM + i] * invN;
    for (int i = t; i < FEAT; i += 256) avg[i] = mbw_sum[b * FEAT + i] * invN;
    __syncthreads();
    for (int s = t; s < SEM; s += 256) {
        float a = b2[s];
        for (int k = 0; k < SEM; ++k) a += mh[k] * w2[(long)k * SEM + s];
        avg[FEAT + s] = a;
    }
    __syncthreads();
    for (int f = t; f < FEAT; f += 256) {
        float a = vfb[f];
        for (int c = 0; c < CAT; ++c) a += avg[c] * vfw[(long)c * FEAT + f];
        gv[b * FEAT + f] = 1.f + 1.f / (1.f + expf(-a));
    }
    for (int s = t; s < SEM; s += 256) {
        float a = sfb[s];
        for (int c = 0; c < CAT; ++c) a += avg[c] * sfw[(long)c * SEM + s];
        gs[b * SEM + s] = 1.f + 1.f / (1.f + expf(-a));
    }
}

__global__ void k_qtot(const float* __restrict__ sf, const float* __restrict__ ssc,
                       const float* __restrict__ wqs, const float* __restrict__ wqss,
                       float* __restrict__ qtot) {
    int row = blockIdx.x, t = threadIdx.x;
    __shared__ float fr[FEAT];
    __shared__ float sr[SEM];
    for (int i = t; i < FEAT; i += 256) fr[i] = sf[(long)row * FEAT + i];
    for (int i = t; i < SEM; i += 256) sr[i] = ssc[(long)row * SEM + i];
    __syncthreads();
    for (int col = t; col < FEAT; col += 256) {
        float a = 0.f;
        for (int k = 0; k < FEAT; ++k) a += fr[k] * wqs[(long)k * FEAT + col];
        for (int k = 0; k < SEM; ++k) a += sr[k] * wqss[(long)k * FEAT + col];
        qtot[(long)row * FEAT + col] = a;
    }
}

__global__ void k_pq1(const float* __restrict__ qtot, const float* __restrict__ wks,
                      const float* __restrict__ wkss, const float* __restrict__ gv,
                      const float* __restrict__ gs, float* __restrict__ pq,
                      float* __restrict__ psem) {
    int b = blockIdx.x, tile = blockIdx.y;
    int t = threadIdx.x;
    __shared__ float q[NWAY][FEAT + 1];
    for (int i = t; i < NWAY * FEAT; i += 256) q[i / FEAT][i % FEAT] = qtot[(long)b * NWAY * FEAT + i];
    __syncthreads();
    for (int item = t; item < 64 * NWAY; item += 256) {
        int cr = tile * 64 + item / NWAY;
        int w = item % NWAY;
        if (cr >= CAT) continue;
        const float* wrow;
        float g;
        if (cr < FEAT) { wrow = wks + (long)cr * FEAT; g = gv[b * FEAT + cr]; }
        else           { wrow = wkss + (long)(cr - FEAT) * FEAT; g = gs[b * SEM + (cr - FEAT)]; }
        float a = 0.f;
        for (int k = 0; k < FEAT; ++k) a += wrow[k] * q[w][k];
        a *= g;
        if (cr < FEAT) pq[((long)b * CAT + cr) * NWAY + w] = a;
        else           psem[((long)b * SEM + (cr - FEAT)) * NWAY + w] = a;
    }
}

__global__ void k_pq2(const float* __restrict__ psem, const float* __restrict__ w2,
                      const float* __restrict__ b2, float* __restrict__ pq,
                      float* __restrict__ cconst) {
    int b = blockIdx.x, tile = blockIdx.y;
    int t = threadIdx.x;
    __shared__ float ps[SEM][NWAY + 1];
    for (int i = t; i < SEM * NWAY; i += 256) ps[i / NWAY][i % NWAY] = psem[(long)b * SEM * NWAY + i];
    __syncthreads();
    for (int item = t; item < 64 * NWAY; item += 256) {
        int tr = tile * 64 + item / NWAY;
        int w = item % NWAY;
        if (tr >= SEM) continue;
        float a = 0.f;
        for (int s = 0; s < SEM; ++s) a += w2[(long)tr * SEM + s] * ps[s][w];
        pq[((long)b * CAT + FEAT + tr) * NWAY + w] = a;
    }
    if (tile == 0 && t < NWAY) {
        float a = 0.f;
        for (int s = 0; s < SEM; ++s) a += b2[s] * ps[s][t];
        cconst[b * NWAY + t] = a;
    }
}

// PQ^T bf16 per batch: [b][w][k 0..840), zero-padded past 812
__global__ void k_prep_pqt(const float* __restrict__ pq, unsigned short* __restrict__ pqt) {
    int b = blockIdx.x, t = threadIdx.x;
    for (int i = t; i < NWAY * 840; i += 256) {
        int w = i / 840, k = i % 840;
        float v = (k < CAT) ? pq[((long)b * CAT + k) * NWAY + w] : 0.f;
        pqt[((long)b * NWAY + w) * 840 + k] = f2bf(v);
    }
}

// scores = [bwh | h] @ PQ^T / temp + const, bf16 MFMA. per-b 8000x16, K=832
__global__ __launch_bounds__(256) void k_scores_mfma(const unsigned short* __restrict__ bwh,
        const unsigned short* __restrict__ h, const unsigned short* __restrict__ pqt,
        const float* __restrict__ cconst, float* __restrict__ scores) {
    __shared__ unsigned short As[128][40];   // [m][k32], +8 pad
    __shared__ unsigned short Bs[NWAY][840]; // [w][k], stride 840 -> 2-way-free
    const int b = blockIdx.y;
    const int bm = blockIdx.x * 128;
    const int t = threadIdx.x;
    const int wv = t >> 6, lane = t & 63;
    const int m16 = lane & 15, q = lane >> 4;
    for (int c = t; c < NWAY * 105; c += 256) {  // stage full PQ^T_b once
        int n = c / 105, j = c % 105;
        *(int4*)(&Bs[n][j * 8]) = *(const int4*)(pqt + ((long)b * NWAY + n) * 840 + j * 8);
    }
    f32x4 acc[2];
    acc[0] = (f32x4){0.f, 0.f, 0.f, 0.f};
    acc[1] = (f32x4){0.f, 0.f, 0.f, 0.f};
    for (int ks = 0; ks < 26; ++ks) {
        int k0 = ks * 32;
        #pragma unroll
        for (int it = 0; it < 4; ++it) {   // A: 128 rows x 8 chunks of 4 bf16
            int c = t + it * 256;
            int row = c >> 3, j = c & 7;
            int gm = bm + row, gk = k0 + j * 4;
            us4 u = (us4){0, 0, 0, 0};
            if (gm < NBASE) {
                if (gk < FEAT)      u = *(const us4*)(bwh + ((long)b * NBASE + gm) * FEAT + gk);
                else if (gk < CAT)  u = *(const us4*)(h + ((long)b * NBASE + gm) * SEM + (gk - FEAT));
            }
            *(us4*)(&As[row][j * 4]) = u;
        }
        __syncthreads();
        bf16x8 bb = *(const bf16x8*)(&Bs[m16][k0 + q * 8]);
        #pragma unroll
        for (int rt = 0; rt < 2; ++rt) {
            bf16x8 a = *(const bf16x8*)(&As[wv * 32 + rt * 16 + m16][q * 8]);
            acc[rt] = __builtin_amdgcn_mfma_f32_16x16x32_bf16(a, bb, acc[rt], 0, 0, 0);
        }
        __syncthreads();
    }
    const float invT = 0.04419417382415922f;  // 1/sqrt(512)
    float cadd = cconst[b * NWAY + m16];
    #pragma unroll
    for (int rt = 0; rt < 2; ++rt) {
        int nrow = bm + wv * 32 + rt * 16 + q * 4;
        #pragma unroll
        for (int r = 0; r < 4; ++r) {
            if (nrow + r < NBASE)
                scores[((long)b * NWAY + m16) * NBASE + nrow + r] = (acc[rt][r] + cadd) * invT;
        }
    }
}

// row softmax over N=8000; probs out in bf16
__global__ void k_softmax(const float* __restrict__ scores, unsigned short* __restrict__ probsb) {
    int row = blockIdx.x;
    int t = threadIdx.x;
    const float* p = scores + (long)row * NBASE;
    __shared__ float red[256];
    float mx = -1e30f;
    for (int i = t; i < NBASE; i += 256) mx = fmaxf(mx, p[i]);
    red[t] = mx;
    __syncthreads();
    for (int off = 128; off > 0; off >>= 1) {
        if (t < off) red[t] = fmaxf(red[t], red[t + off]);
        __syncthreads();
    }
    mx = red[0];
    __syncthreads();
    float sum = 0.f;
    for (int i = t; i < NBASE; i += 256) sum += expf(p[i] - mx);
    red[t] = sum;
    __syncthreads();
    for (int off = 128; off > 0; off >>= 1) {
        if (t < off) red[t] += red[t + off];
        __syncthreads();
    }
    float inv = 1.0f / red[0];
    for (int i = t; i < NBASE; i += 256) probsb[(long)row * NBASE + i] = f2bf(expf(p[i] - mx) * inv);
}

// ov[b,w,f] = sum_n probs * bw   (bf16 inputs, fp32 atomic accum)
__global__ void k_ov(const unsigned short* __restrict__ probsb, const unsigned short* __restrict__ bwh,
                     float* __restrict__ ov) {
    int b = blockIdx.x, ch = blockIdx.y;
    int t = threadIdx.x;
    __shared__ float pr[NWAY][500];
    for (int i = t; i < NWAY * 500; i += 256) {
        int w = i / 500, j = i % 500;
        pr[w][j] = bf2f(probsb[((long)b * NWAY + w) * NBASE + (long)ch * 500 + j]);
    }
    __syncthreads();
    float a0[NWAY], a1[NWAY];
    #pragma unroll
    for (int w = 0; w < NWAY; ++w) { a0[w] = 0.f; a1[w] = 0.f; }
    const unsigned short* bp = bwh + ((long)b * NBASE + (long)ch * 500) * FEAT + 2 * t;
    for (int j = 0; j < 500; ++j) {
        us2 u = *(const us2*)(bp + (long)j * FEAT);
        float v0 = bf2f(u.x), v1 = bf2f(u.y);
        #pragma unroll
        for (int w = 0; w < NWAY; ++w) {
            a0[w] += pr[w][j] * v0;
            a1[w] += pr[w][j] * v1;
        }
    }
    for (int w = 0; w < NWAY; ++w) {
        atomicAdd(&ov[((long)b * NWAY + w) * FEAT + 2 * t], a0[w]);
        atomicAdd(&ov[((long)b * NWAY + w) * FEAT + 2 * t + 1], a1[w]);
    }
}

__global__ void k_small_gemm(const float* __restrict__ A, const float* __restrict__ Wm,
                             const float* __restrict__ Res, float* __restrict__ Out) {
    int row = blockIdx.x, t = threadIdx.x;
    __shared__ float ar[FEAT];
    for (int i = t; i < FEAT; i += 256) ar[i] = A[(long)row * FEAT + i];
    __syncthreads();
    for (int col = t; col < FEAT; col += 256) {
        float a = 0.f;
        for (int k = 0; k < FEAT; ++k) a += ar[k] * Wm[(long)k * FEAT + col];
        if (Res) a += Res[(long)row * FEAT + col];
        Out[(long)row * FEAT + col] = a;
    }
}

extern "C" void kernel_launch(void* const* d_in, const int* in_sizes, int n_in,
                              void* d_out, int out_size, void* d_ws, size_t ws_size,
                              hipStream_t stream) {
    (void)in_sizes; (void)n_in; (void)out_size; (void)ws_size;
    const float* sf   = (const float*)d_in[0];
    const float* bw   = (const float*)d_in[1];
    const float* ssm  = (const float*)d_in[2];
    const float* bsm  = (const float*)d_in[3];
    const float* mw1  = (const float*)d_in[4];
    const float* mb1  = (const float*)d_in[5];
    const float* mw2  = (const float*)d_in[6];
    const float* mb2  = (const float*)d_in[7];
    const float* vfw  = (const float*)d_in[8];
    const float* vfb  = (const float*)d_in[9];
    const float* sfw  = (const float*)d_in[10];
    const float* sfb  = (const float*)d_in[11];
    const float* wqs  = (const float*)d_in[12];
    const float* wks  = (const float*)d_in[13];
    const float* wvs  = (const float*)d_in[14];
    const float* wqss = (const float*)d_in[15];
    const float* wkss = (const float*)d_in[16];
    const float* fcw  = (const float*)d_in[17];

    float* out = (float*)d_out;
    float* scores = out + NB * NWAY * FEAT;  // d_out = [out | attn_score]

    char* wsb = (char*)d_ws;
    unsigned short* bwh    = (unsigned short*)(wsb);
    unsigned short* h      = (unsigned short*)(wsb + 65536000L);
    unsigned short* w1t    = (unsigned short*)(wsb + 103936000L);
    unsigned short* pqt    = (unsigned short*)(wsb + 104140800L);
    unsigned short* probsb = (unsigned short*)(wsb + 104355840L);
    float* mbw    = (float*)(wsb + 106403840L);
    float* mh     = (float*)(wsb + 106420224L);
    float* gv     = (float*)(wsb + 106429824L);
    float* gs     = (float*)(wsb + 106446208L);
    float* ssc    = (float*)(wsb + 106455808L);
    float* qtot   = (float*)(wsb + 106609408L);
    float* psem   = (float*)(wsb + 106871552L);
    float* pq     = (float*)(wsb + 107025152L);
    float* cconst = (float*)(wsb + 107440896L);
    float* ov     = (float*)(wsb + 107441408L);
    float* tmp    = (float*)(wsb + 107703552L);

    // zero accumulators (ws is re-poisoned before every launch)
    hipMemsetAsync(mbw, 0, (NB * FEAT + NB * SEM) * sizeof(float), stream);
    hipMemsetAsync(ov, 0, NB * NWAY * FEAT * sizeof(float), stream);

    k_cvt_bw<<<dim3(NB, 50), 256, 0, stream>>>(bw, bwh, mbw);
    k_prep_w1t<<<320, 320, 0, stream>>>(mw1, w1t);
    k_hgemm_mfma<<<1000, 256, 0, stream>>>(bsm, w1t, mb1, h);
    k_mean_h_bf<<<dim3(NB, 20), 320, 0, stream>>>(h, mh);
    k_ssc<<<NB * NWAY, 320, 0, stream>>>(ssm, mw1, mb1, mw2, mb2, ssc);
    k_gates<<<NB, 256, 0, stream>>>(mbw, mh, mw2, mb2, vfw, vfb, sfw, sfb, gv, gs);
    k_qtot<<<NB * NWAY, 256, 0, stream>>>(sf, ssc, wqs, wqss, qtot);
    k_pq1<<<dim3(NB, 13), 256, 0, stream>>>(qtot, wks, wkss, gv, gs, pq, psem);
    k_pq2<<<dim3(NB, 5), 256, 0, stream>>>(psem, mw2, mb2, pq, cconst);
    k_prep_pqt<<<NB, 256, 0, stream>>>(pq, pqt);
    k_scores_mfma<<<dim3(63, NB), 256, 0, stream>>>(bwh, h, pqt, cconst, scores);
    k_softmax<<<NB * NWAY, 256, 0, stream>>>(scores, probsb);
    k_ov<<<dim3(NB, 16), 256, 0, stream>>>(probsb, bwh, ov);
    k_small_gemm<<<NB * NWAY, 256, 0, stream>>>(ov, wvs, nullptr, tmp);
    k_small_gemm<<<NB * NWAY, 256, 0, stream>>>(tmp, fcw, sf, out);
}

// Round 3
// 727.196 us; speedup vs baseline: 1.7834x; 1.2597x over previous
//
#include <hip/hip_runtime.h>

#define NB 8
#define NWAY 16
#define NBASE 8000
#define FEAT 512
#define SEM 300
#define CAT (FEAT + SEM)  // 812

typedef __attribute__((ext_vector_type(8))) short bf16x8;
typedef __attribute__((ext_vector_type(4))) float f32x4;
typedef __attribute__((ext_vector_type(4))) unsigned short us4;
typedef __attribute__((ext_vector_type(2))) unsigned short us2;
typedef unsigned short us;

__device__ __forceinline__ us f2bf(float x) {
    union { float f; unsigned int u; } v; v.f = x;
    unsigned int r = v.u + 0x7FFFu + ((v.u >> 16) & 1u);
    return (us)(r >> 16);
}
__device__ __forceinline__ float bf2f(us u) {
    union { unsigned int u; float f; } v; v.u = ((unsigned int)u) << 16;
    return v.f;
}

// =============== workspace byte offsets ===============
constexpr long O_BWH   = 0L;            // 8*8000*512*2  = 65,536,000
constexpr long O_H     = 65536000L;     // 8*8000*300*2  = 38,400,000
constexpr long O_PROBS = 103936000L;    // 8*16*8000*2   =  2,048,000  (aliases w1t/w2t/qwT below)
constexpr long O_W1T   = 103936000L;    // 320*320*2 = 204,800   (dead before softmax)
constexpr long O_W2T   = 104140800L;    // 320*320*2 = 204,800
constexpr long O_QWT   = 104345600L;    // 512*832*2 = 851,968
constexpr long O_AVG   = 105197568L;    // 8*812*4 = 25,984      (dead before softmax)
constexpr long O_PSEMT = 105223552L;    // 128*304*4 = 155,648   (dead before softmax)
constexpr long O_WVST  = 105984000L;    // 512*512*2 = 524,288
constexpr long O_FCWT  = 106508288L;    // 512*512*2 = 524,288
constexpr long O_PQT   = 107032576L;    // 8*16*840*2 = 215,040
constexpr long O_F     = 107247616L;    // float scratch:
constexpr long O_MBW   = O_F;           // 8*512*4 = 16,384
constexpr long O_MH    = O_F + 16384;   // 8*300*4 = 9,600
constexpr long O_GV    = O_F + 25984;   // 16,384
constexpr long O_GS    = O_F + 42368;   // 9,600
constexpr long O_SSCH  = O_F + 51968;   // 128*300*4 = 153,600   (tmp aliases here later)
constexpr long O_SSC   = O_F + 205568;  // 153,600
constexpr long O_QTOT  = O_F + 359168;  // 128*512*4 = 262,144   (ov aliases here later)
constexpr long O_CC    = O_F + 621312;  // 128*4 = 512
constexpr long O_TMP   = O_SSCH;        // 262,144 over sscH+ssc (dead)
constexpr long O_OV    = O_QTOT;        // 262,144 over qtot (dead)
// end = O_F + 621,824 -> 107,869,440 bytes total

// =============== weight prep: bf16 transposes ===============
// op0: w1t[320][320] = w1^T pad; op1: w2t = w2^T pad; op2: qwT[512][832] = [wqs;wqss]^T
// op3: wvsT[512][512]; op4: fcwT[512][512]
__global__ void k_prep(const float* __restrict__ w1, const float* __restrict__ w2,
                       const float* __restrict__ wqs, const float* __restrict__ wqss,
                       const float* __restrict__ wvs, const float* __restrict__ fcw,
                       us* __restrict__ w1t, us* __restrict__ w2t, us* __restrict__ qwT,
                       us* __restrict__ wvsT, us* __restrict__ fcwT) {
    long e = (long)blockIdx.x * 256 + threadIdx.x;
    switch (blockIdx.y) {
    case 0: if (e < 320 * 320) { int n = e / 320, k = e % 320;
            w1t[e] = f2bf((n < SEM && k < SEM) ? w1[(long)k * SEM + n] : 0.f); } break;
    case 1: if (e < 320 * 320) { int n = e / 320, k = e % 320;
            w2t[e] = f2bf((n < SEM && k < SEM) ? w2[(long)k * SEM + n] : 0.f); } break;
    case 2: if (e < 512 * 832) { int n = e / 832, k = e % 832;
            float v = 0.f;
            if (k < FEAT) v = wqs[(long)k * FEAT + n];
            else if (k < CAT) v = wqss[(long)(k - FEAT) * FEAT + n];
            qwT[e] = f2bf(v); } break;
    case 3: if (e < 512 * 512) { int n = e / 512, k = e % 512;
            wvsT[e] = f2bf(wvs[(long)k * FEAT + n]); } break;
    case 4: if (e < 512 * 512) { int n = e / 512, k = e % 512;
            fcwT[e] = f2bf(fcw[(long)k * FEAT + n]); } break;
    }
}

// =============== bw -> bf16 + column sums ===============
__global__ void k_cvt_bw(const float* __restrict__ bw, us* __restrict__ bwh,
                         float* __restrict__ mbw) {
    int b = blockIdx.x, ch = blockIdx.y;  // 50 chunks of 160 rows
    int t = threadIdx.x;
    int cg = t & 127, rs = t >> 7;
    long base = ((long)b * NBASE + (long)ch * 160) * FEAT;
    float s0 = 0.f, s1 = 0.f, s2 = 0.f, s3 = 0.f;
    for (int r = rs; r < 160; r += 2) {
        float4 v = *(const float4*)(bw + base + (long)r * FEAT + cg * 4);
        us4 u; u.x = f2bf(v.x); u.y = f2bf(v.y); u.z = f2bf(v.z); u.w = f2bf(v.w);
        *(us4*)(bwh + base + (long)r * FEAT + cg * 4) = u;
        s0 += v.x; s1 += v.y; s2 += v.z; s3 += v.w;
    }
    atomicAdd(&mbw[b * FEAT + cg * 4 + 0], s0);
    atomicAdd(&mbw[b * FEAT + cg * 4 + 1], s1);
    atomicAdd(&mbw[b * FEAT + cg * 4 + 2], s2);
    atomicAdd(&mbw[b * FEAT + cg * 4 + 3], s3);
}

// =============== h = leaky(bsm @ W1 + b1), fused column sums, coalesced store ===============
__global__ __launch_bounds__(256) void k_hgemm_mfma(const float* __restrict__ X,
        const us* __restrict__ W1T, const float* __restrict__ b1,
        us* __restrict__ H, float* __restrict__ mh) {
    __shared__ char smem[64 * 72 * 2 + 320 * 72 * 2];  // 55,296 B
    us (*As)[72] = (us(*)[72])smem;
    us (*Bs)[72] = (us(*)[72])(smem + 64 * 72 * 2);
    us (*Cs)[304] = (us(*)[304])smem;  // epilogue alias (38,912 B)
    const int bm = blockIdx.x * 64;
    const int bb = blockIdx.x / 125;
    const int t = threadIdx.x;
    const int wv = t >> 6, lane = t & 63;
    const int m16 = lane & 15, q = lane >> 4;
    f32x4 acc[4][5];
    #pragma unroll
    for (int i = 0; i < 4; ++i)
        #pragma unroll
        for (int j = 0; j < 5; ++j) acc[i][j] = (f32x4){0.f, 0.f, 0.f, 0.f};
    for (int ks = 0; ks < 5; ++ks) {
        const int k0 = ks * 64;
        #pragma unroll
        for (int it = 0; it < 4; ++it) {
            int c = t + it * 256;
            int row = c >> 4, j = c & 15;
            int gk = k0 + j * 4;
            float4 v = make_float4(0.f, 0.f, 0.f, 0.f);
            if (gk < SEM) v = *(const float4*)(X + (long)(bm + row) * SEM + gk);
            us4 u; u.x = f2bf(v.x); u.y = f2bf(v.y); u.z = f2bf(v.z); u.w = f2bf(v.w);
            *(us4*)(&As[row][j * 4]) = u;
        }
        #pragma unroll
        for (int it = 0; it < 10; ++it) {
            int c = t + it * 256;
            int n = c >> 3, j = c & 7;
            int4 v = *(const int4*)(W1T + (long)n * 320 + k0 + j * 8);
            *(int4*)(&Bs[n][j * 8]) = v;
        }
        __syncthreads();
        #pragma unroll
        for (int kc = 0; kc < 64; kc += 32) {
            bf16x8 a[4], bbv[5];
            #pragma unroll
            for (int rt = 0; rt < 4; ++rt)
                a[rt] = *(const bf16x8*)(&As[rt * 16 + m16][kc + q * 8]);
            #pragma unroll
            for (int ct = 0; ct < 5; ++ct)
                bbv[ct] = *(const bf16x8*)(&Bs[(wv * 5 + ct) * 16 + m16][kc + q * 8]);
            #pragma unroll
            for (int rt = 0; rt < 4; ++rt)
                #pragma unroll
                for (int ct = 0; ct < 5; ++ct)
                    acc[rt][ct] = __builtin_amdgcn_mfma_f32_16x16x32_bf16(a[rt], bbv[ct], acc[rt][ct], 0, 0, 0);
        }
        __syncthreads();
    }
    // epilogue: bias+leaky, stash in Cs (aliases As/Bs — safe: all LDS reads done), col sums
    float csum[5] = {0.f, 0.f, 0.f, 0.f, 0.f};
    #pragma unroll
    for (int ct = 0; ct < 5; ++ct) {
        int col = (wv * 5 + ct) * 16 + m16;
        float bias = (col < SEM) ? b1[col] : 0.f;
        #pragma unroll
        for (int rt = 0; rt < 4; ++rt) {
            #pragma unroll
            for (int r = 0; r < 4; ++r) {
                float v = acc[rt][ct][r] + bias;
                v = v > 0.f ? v : 0.1f * v;
                if (col < SEM) { Cs[rt * 16 + q * 4 + r][col] = f2bf(v); csum[ct] += v; }
            }
        }
    }
    #pragma unroll
    for (int ct = 0; ct < 5; ++ct) {
        float s = csum[ct];
        s += __shfl_xor(s, 16);
        s += __shfl_xor(s, 32);
        int col = (wv * 5 + ct) * 16 + m16;
        if (q == 0 && col < SEM) atomicAdd(&mh[bb * SEM + col], s);
    }
    __syncthreads();
    for (int i = t; i < 64 * 75; i += 256) {
        int row = i / 75, j = i % 75;
        *(us4*)(H + (long)(bm + row) * SEM + j * 4) = *(const us4*)(&Cs[row][j * 4]);
    }
}

// =============== avg vector: [mean(bw) | mean(h)@w2 + b2] ===============
__global__ void k_avg(const float* __restrict__ mbw, const float* __restrict__ mh,
                      const float* __restrict__ w2, const float* __restrict__ b2,
                      float* __restrict__ avg) {
    int x = blockIdx.x, b = blockIdx.y, t = threadIdx.x;
    const float invN = 1.0f / NBASE;
    if (x == 5) {
        for (int i = t; i < FEAT; i += 256) avg[b * CAT + i] = mbw[b * FEAT + i] * invN;
        return;
    }
    __shared__ float mhL[SEM];
    __shared__ float red[4][64];
    for (int i = t; i < SEM; i += 256) mhL[i] = mh[b * SEM + i] * invN;
    __syncthreads();
    int s = x * 64 + (t & 63);
    int kq = t >> 6;
    float a = 0.f;
    if (s < SEM)
        for (int c = kq * 75; c < kq * 75 + 75; ++c) a += mhL[c] * w2[(long)c * SEM + s];
    red[kq][t & 63] = a;
    __syncthreads();
    if (kq == 0 && s < SEM)
        avg[b * CAT + FEAT + s] = red[0][t & 63] + red[1][t & 63] + red[2][t & 63] + red[3][t & 63] + b2[s];
}

// =============== gates matvec: gv/gs = 1+sigmoid(avg @ W + b) ===============
__global__ void k_gates_mv(const float* __restrict__ avg, const float* __restrict__ vfw,
                           const float* __restrict__ vfb, const float* __restrict__ sfw,
                           const float* __restrict__ sfb, float* __restrict__ gv,
                           float* __restrict__ gs) {
    int tile = blockIdx.x, b = blockIdx.y, t = threadIdx.x;
    __shared__ float avgL[CAT];
    __shared__ float red[4][64];
    for (int i = t; i < CAT; i += 256) avgL[i] = avg[b * CAT + i];
    __syncthreads();
    int l = t & 63, kq = t >> 6;
    float a = 0.f;
    if (tile < 8) {
        int f = tile * 64 + l;
        for (int c = kq * 203; c < kq * 203 + 203; ++c) a += avgL[c] * vfw[(long)c * FEAT + f];
        red[kq][l] = a;
        __syncthreads();
        if (kq == 0) {
            float s = red[0][l] + red[1][l] + red[2][l] + red[3][l] + vfb[f];
            gv[b * FEAT + f] = 1.f + 1.f / (1.f + expf(-s));
        }
    } else {
        int fs = (tile - 8) * 64 + l;
        if (fs < SEM)
            for (int c = kq * 203; c < kq * 203 + 203; ++c) a += avgL[c] * sfw[(long)c * SEM + fs];
        red[kq][l] = a;
        __syncthreads();
        if (kq == 0 && fs < SEM) {
            float s = red[0][l] + red[1][l] + red[2][l] + red[3][l] + sfb[fs];
            gs[b * SEM + fs] = 1.f + 1.f / (1.f + expf(-s));
        }
    }
}

// =============== generic M=128 MFMA GEMM, 8 modes ===============
// MODE: 0 ssc1(leaky,bias) 1 ssc2(bias) 2 qtot(concat A) 3 zvis(gate->pqt bf16)
//       4 zsem(gate->psemT f32) 5 zfold(->pqt+512 bf16) 6 ov@wvsT 7 final(+res)
constexpr int MM_K[8]    = {300, 300, 812, 512, 512, 300, 512, 512};
constexpr int MM_K1[8]   = {300, 300, 512, 512, 512, 300, 512, 512};
constexpr int MM_KP[8]   = {320, 320, 832, 512, 512, 320, 512, 512};
constexpr int MM_N[8]    = {300, 300, 512, 512, 300, 300, 512, 512};
constexpr int MM_LDB[8]  = {320, 320, 832, 512, 512, 300, 512, 512};
constexpr int MM_LDA0[8] = {300, 300, 512, 512, 512, 304, 512, 512};
constexpr bool MM_BBF[8] = {true, true, true, false, false, false, true, true};

template <int MODE>
__global__ __launch_bounds__(256) void k_mm(const float* __restrict__ A0,
        const float* __restrict__ A1, const void* __restrict__ Bv,
        const float* __restrict__ bias, const float* __restrict__ gate,
        const float* __restrict__ res, float* __restrict__ Cf, us* __restrict__ Cb) {
    constexpr int K = MM_K[MODE], K1 = MM_K1[MODE], KP = MM_KP[MODE];
    constexpr int N = MM_N[MODE], LDB = MM_LDB[MODE], LDA0 = MM_LDA0[MODE];
    __shared__ us As[128][40];
    __shared__ us Bs[64][40];
    const int n0 = blockIdx.x * 64;
    const int t = threadIdx.x;
    const int wv = t >> 6, lane = t & 63;
    const int m16 = lane & 15, q = lane >> 4;
    const int wm = wv >> 1, wn = wv & 1;
    f32x4 acc[4][2];
    #pragma unroll
    for (int i = 0; i < 4; ++i) { acc[i][0] = (f32x4){0,0,0,0}; acc[i][1] = (f32x4){0,0,0,0}; }
    for (int ks = 0; ks < KP / 32; ++ks) {
        const int k0 = ks * 32;
        #pragma unroll
        for (int it = 0; it < 4; ++it) {  // A: 128 rows x 8 float4 groups
            int idx = t + it * 256;
            int row = idx >> 3, j = idx & 7;
            int gk = k0 + j * 4;
            float4 v = make_float4(0.f, 0.f, 0.f, 0.f);
            if (gk < K1) v = *(const float4*)(A0 + (long)row * LDA0 + gk);
            else if constexpr (K1 < K) {
                if (gk < K) v = *(const float4*)(A1 + (long)row * 300 + (gk - K1));
            }
            us4 u; u.x = f2bf(v.x); u.y = f2bf(v.y); u.z = f2bf(v.z); u.w = f2bf(v.w);
            *(us4*)(&As[row][j * 4]) = u;
        }
        if constexpr (MM_BBF[MODE]) {  // bf16 B, padded: guard-free
            int n = t >> 2, j = t & 3;
            *(int4*)(&Bs[n][j * 8]) = *(const int4*)((const us*)Bv + (long)(n0 + n) * LDB + k0 + j * 8);
        } else {  // fp32 (N x K) B with cvt
            #pragma unroll
            for (int it = 0; it < 2; ++it) {
                int idx = t + it * 256;
                int n = idx >> 3, j = idx & 7;
                int gk = k0 + j * 4;
                float4 v = make_float4(0.f, 0.f, 0.f, 0.f);
                if ((N == 512 || n0 + n < N) && gk < K)
                    v = *(const float4*)((const float*)Bv + (long)(n0 + n) * LDB + gk);
                us4 u; u.x = f2bf(v.x); u.y = f2bf(v.y); u.z = f2bf(v.z); u.w = f2bf(v.w);
                *(us4*)(&Bs[n][j * 4]) = u;
            }
        }
        __syncthreads();
        bf16x8 a[4], bb[2];
        #pragma unroll
        for (int rt = 0; rt < 4; ++rt) a[rt] = *(const bf16x8*)(&As[wm * 64 + rt * 16 + m16][q * 8]);
        #pragma unroll
        for (int ct = 0; ct < 2; ++ct) bb[ct] = *(const bf16x8*)(&Bs[wn * 32 + ct * 16 + m16][q * 8]);
        #pragma unroll
        for (int rt = 0; rt < 4; ++rt)
            #pragma unroll
            for (int ct = 0; ct < 2; ++ct)
                acc[rt][ct] = __builtin_amdgcn_mfma_f32_16x16x32_bf16(a[rt], bb[ct], acc[rt][ct], 0, 0, 0);
        __syncthreads();
    }
    #pragma unroll
    for (int rt = 0; rt < 4; ++rt) {
        #pragma unroll
        for (int ct = 0; ct < 2; ++ct) {
            int col = n0 + wn * 32 + ct * 16 + m16;
            if (N != 512 && col >= N) continue;
            #pragma unroll
            for (int r = 0; r < 4; ++r) {
                int row = wm * 64 + rt * 16 + q * 4 + r;
                float v = acc[rt][ct][r];
                if constexpr (MODE == 0) {
                    v += bias[col]; v = v > 0.f ? v : 0.1f * v;
                    Cf[(long)row * 300 + col] = v;
                } else if constexpr (MODE == 1) {
                    Cf[(long)row * 300 + col] = v + bias[col];
                } else if constexpr (MODE == 2 || MODE == 6) {
                    Cf[(long)row * 512 + col] = v;
                } else if constexpr (MODE == 3) {
                    Cb[(long)row * 840 + col] = f2bf(gate[(row >> 4) * FEAT + col] * v);
                } else if constexpr (MODE == 4) {
                    Cf[(long)row * 304 + col] = gate[(row >> 4) * SEM + col] * v;
                } else if constexpr (MODE == 5) {
                    Cb[(long)row * 840 + 512 + col] = f2bf(v);
                } else if constexpr (MODE == 7) {
                    Cf[(long)row * 512 + col] = v + res[(long)row * 512 + col];
                }
            }
        }
    }
}

// =============== cconst[b,w] = psemT[b*16+w] . b2 ===============
__global__ void k_cconst(const float* __restrict__ psemT, const float* __restrict__ b2,
                         float* __restrict__ cconst) {
    int b = blockIdx.x, t = threadIdx.x;
    int w = t >> 4, l = t & 15;
    float a = 0.f;
    for (int s = l; s < SEM; s += 16) a += psemT[(long)(b * NWAY + w) * 304 + s] * b2[s];
    a += __shfl_xor(a, 1); a += __shfl_xor(a, 2);
    a += __shfl_xor(a, 4); a += __shfl_xor(a, 8);
    if (l == 0) cconst[b * NWAY + w] = a;
}

// =============== scores = [bwh | h] @ pqt^T * invT + cconst ===============
__global__ __launch_bounds__(256) void k_scores_mfma(const us* __restrict__ bwh,
        const us* __restrict__ h, const us* __restrict__ pqt,
        const float* __restrict__ cconst, float* __restrict__ scores) {
    __shared__ us As[128][40];
    __shared__ us Bs[NWAY][840];
    const int b = blockIdx.y;
    const int bm = blockIdx.x * 128;
    const int t = threadIdx.x;
    const int wv = t >> 6, lane = t & 63;
    const int m16 = lane & 15, q = lane >> 4;
    for (int c = t; c < NWAY * 105; c += 256) {
        int n = c / 105, j = c % 105;
        *(int4*)(&Bs[n][j * 8]) = *(const int4*)(pqt + ((long)b * NWAY + n) * 840 + j * 8);
    }
    f32x4 acc[2];
    acc[0] = (f32x4){0,0,0,0};
    acc[1] = (f32x4){0,0,0,0};
    for (int ks = 0; ks < 26; ++ks) {
        int k0 = ks * 32;
        #pragma unroll
        for (int it = 0; it < 4; ++it) {
            int c = t + it * 256;
            int row = c >> 3, j = c & 7;
            int gm = bm + row, gk = k0 + j * 4;
            us4 u = (us4){0, 0, 0, 0};
            if (gm < NBASE) {
                if (gk < FEAT)      u = *(const us4*)(bwh + ((long)b * NBASE + gm) * FEAT + gk);
                else if (gk < CAT)  u = *(const us4*)(h + ((long)b * NBASE + gm) * SEM + (gk - FEAT));
            }
            *(us4*)(&As[row][j * 4]) = u;
        }
        __syncthreads();
        bf16x8 bb = *(const bf16x8*)(&Bs[m16][k0 + q * 8]);
        #pragma unroll
        for (int rt = 0; rt < 2; ++rt) {
            bf16x8 a = *(const bf16x8*)(&As[wv * 32 + rt * 16 + m16][q * 8]);
            acc[rt] = __builtin_amdgcn_mfma_f32_16x16x32_bf16(a, bb, acc[rt], 0, 0, 0);
        }
        __syncthreads();
    }
    const float invT = 0.04419417382415922f;  // 1/sqrt(512)
    float cadd = cconst[b * NWAY + m16];
    #pragma unroll
    for (int rt = 0; rt < 2; ++rt) {
        int nrow = bm + wv * 32 + rt * 16 + q * 4;
        if (nrow < NBASE) {
            float4 st;
            st.x = (acc[rt][0] + cadd) * invT;
            st.y = (acc[rt][1] + cadd) * invT;
            st.z = (acc[rt][2] + cadd) * invT;
            st.w = (acc[rt][3] + cadd) * invT;
            *(float4*)(scores + ((long)b * NWAY + m16) * NBASE + nrow) = st;
        }
    }
}

// =============== softmax over N=8000, bf16 probs out ===============
__global__ void k_softmax(const float* __restrict__ scores, us* __restrict__ probsb) {
    int row = blockIdx.x;
    int t = threadIdx.x;
    const float* p = scores + (long)row * NBASE;
    __shared__ float red[256];
    float mx = -1e30f;
    for (int i = t; i < NBASE; i += 256) mx = fmaxf(mx, p[i]);
    red[t] = mx;
    __syncthreads();
    for (int off = 128; off > 0; off >>= 1) {
        if (t < off) red[t] = fmaxf(red[t], red[t + off]);
        __syncthreads();
    }
    mx = red[0];
    __syncthreads();
    float sum = 0.f;
    for (int i = t; i < NBASE; i += 256) sum += expf(p[i] - mx);
    red[t] = sum;
    __syncthreads();
    for (int off = 128; off > 0; off >>= 1) {
        if (t < off) red[t] += red[t + off];
        __syncthreads();
    }
    float inv = 1.0f / red[0];
    for (int i = t; i < NBASE; i += 256) probsb[(long)row * NBASE + i] = f2bf(expf(p[i] - mx) * inv);
}

// =============== ov = probs @ bwh (320 blocks, fp32 atomics) ===============
__global__ void k_ov(const us* __restrict__ probsb, const us* __restrict__ bwh,
                     float* __restrict__ ov) {
    int b = blockIdx.x, ch = blockIdx.y;  // 40 chunks of 200 n
    int t = threadIdx.x;
    __shared__ float pr[NWAY][200];
    for (int i = t; i < NWAY * 200; i += 256) {
        int w = i / 200, j = i % 200;
        pr[w][j] = bf2f(probsb[((long)b * NWAY + w) * NBASE + (long)ch * 200 + j]);
    }
    __syncthreads();
    float a0[NWAY], a1[NWAY];
    #pragma unroll
    for (int w = 0; w < NWAY; ++w) { a0[w] = 0.f; a1[w] = 0.f; }
    const us* bp = bwh + ((long)b * NBASE + (long)ch * 200) * FEAT + 2 * t;
    for (int j = 0; j < 200; ++j) {
        us2 u = *(const us2*)(bp + (long)j * FEAT);
        float v0 = bf2f(u.x), v1 = bf2f(u.y);
        #pragma unroll
        for (int w = 0; w < NWAY; ++w) {
            a0[w] += pr[w][j] * v0;
            a1[w] += pr[w][j] * v1;
        }
    }
    for (int w = 0; w < NWAY; ++w) {
        atomicAdd(&ov[((long)b * NWAY + w) * FEAT + 2 * t], a0[w]);
        atomicAdd(&ov[((long)b * NWAY + w) * FEAT + 2 * t + 1], a1[w]);
    }
}

extern "C" void kernel_launch(void* const* d_in, const int* in_sizes, int n_in,
                              void* d_out, int out_size, void* d_ws, size_t ws_size,
                              hipStream_t stream) {
    (void)in_sizes; (void)n_in; (void)out_size; (void)ws_size;
    const float* sf   = (const float*)d_in[0];
    const float* bw   = (const float*)d_in[1];
    const float* ssm  = (const float*)d_in[2];
    const float* bsm  = (const float*)d_in[3];
    const float* mw1  = (const float*)d_in[4];
    const float* mb1  = (const float*)d_in[5];
    const float* mw2  = (const float*)d_in[6];
    const float* mb2  = (const float*)d_in[7];
    const float* vfw  = (const float*)d_in[8];
    const float* vfb  = (const float*)d_in[9];
    const float* sfw  = (const float*)d_in[10];
    const float* sfb  = (const float*)d_in[11];
    const float* wqs  = (const float*)d_in[12];
    const float* wks  = (const float*)d_in[13];
    const float* wvs  = (const float*)d_in[14];
    const float* wqss = (const float*)d_in[15];
    const float* wkss = (const float*)d_in[16];
    const float* fcw  = (const float*)d_in[17];

    float* out = (float*)d_out;
    float* scores = out + NB * NWAY * FEAT;  // d_out = [out | attn_score]

    char* wsb = (char*)d_ws;
    us* bwh    = (us*)(wsb + O_BWH);
    us* h      = (us*)(wsb + O_H);
    us* probsb = (us*)(wsb + O_PROBS);
    us* w1t    = (us*)(wsb + O_W1T);
    us* w2t    = (us*)(wsb + O_W2T);
    us* qwT    = (us*)(wsb + O_QWT);
    us* wvsT   = (us*)(wsb + O_WVST);
    us* fcwT   = (us*)(wsb + O_FCWT);
    us* pqt    = (us*)(wsb + O_PQT);
    float* avgv   = (float*)(wsb + O_AVG);
    float* psemT  = (float*)(wsb + O_PSEMT);
    float* mbw    = (float*)(wsb + O_MBW);
    float* mh     = (float*)(wsb + O_MH);
    float* gv     = (float*)(wsb + O_GV);
    float* gs     = (float*)(wsb + O_GS);
    float* sscH   = (float*)(wsb + O_SSCH);
    float* ssc    = (float*)(wsb + O_SSC);
    float* qtot   = (float*)(wsb + O_QTOT);
    float* cconst = (float*)(wsb + O_CC);
    float* tmp    = (float*)(wsb + O_TMP);
    float* ov     = (float*)(wsb + O_OV);

    hipMemsetAsync(mbw, 0, (NB * FEAT + NB * SEM) * sizeof(float), stream);  // mbw+mh contiguous
    hipMemsetAsync(pqt, 0, (long)NB * NWAY * 840 * 2, stream);               // pad cols must be 0

    k_prep<<<dim3(1664, 5), 256, 0, stream>>>(mw1, mw2, wqs, wqss, wvs, fcw, w1t, w2t, qwT, wvsT, fcwT);
    k_cvt_bw<<<dim3(NB, 50), 256, 0, stream>>>(bw, bwh, mbw);
    k_hgemm_mfma<<<1000, 256, 0, stream>>>(bsm, w1t, mb1, h, mh);
    k_avg<<<dim3(6, NB), 256, 0, stream>>>(mbw, mh, mw2, mb2, avgv);
    k_gates_mv<<<dim3(13, NB), 256, 0, stream>>>(avgv, vfw, vfb, sfw, sfb, gv, gs);
    // ssc two-layer MLP
    k_mm<0><<<5, 256, 0, stream>>>(ssm, nullptr, w1t, mb1, nullptr, nullptr, sscH, nullptr);
    k_mm<1><<<5, 256, 0, stream>>>(sscH, nullptr, w2t, mb2, nullptr, nullptr, ssc, nullptr);
    // qtot = [sf|ssc] @ qwT^T
    k_mm<2><<<8, 256, 0, stream>>>(sf, ssc, qwT, nullptr, nullptr, nullptr, qtot, nullptr);
    // zvis -> pqt[:,0:512] (gv fused), zsem -> psemT (gs fused), zfold -> pqt[:,512:812]
    k_mm<3><<<8, 256, 0, stream>>>(qtot, nullptr, wks, nullptr, gv, nullptr, nullptr, pqt);
    k_mm<4><<<5, 256, 0, stream>>>(qtot, nullptr, wkss, nullptr, gs, nullptr, psemT, nullptr);
    k_mm<5><<<5, 256, 0, stream>>>(psemT, nullptr, mw2, nullptr, nullptr, nullptr, nullptr, pqt);
    k_cconst<<<NB, 256, 0, stream>>>(psemT, mb2, cconst);
    k_scores_mfma<<<dim3(63, NB), 256, 0, stream>>>(bwh, h, pqt, cconst, scores);
    k_softmax<<<NB * NWAY, 256, 0, stream>>>(scores, probsb);
    hipMemsetAsync(ov, 0, NB * NWAY * FEAT * sizeof(float), stream);
    k_ov<<<dim3(NB, 40), 256, 0, stream>>>(probsb, bwh, ov);
    k_mm<6><<<8, 256, 0, stream>>>(ov, nullptr, wvsT, nullptr, nullptr, nullptr, tmp, nullptr);
    k_mm<7><<<8, 256, 0, stream>>>(tmp, nullptr, fcwT, nullptr, nullptr, sf, out, nullptr);
}

// Round 4
// 694.825 us; speedup vs baseline: 1.8665x; 1.0466x over previous
//
#include <hip/hip_runtime.h>

#define NB 8
#define NWAY 16
#define NBASE 8000
#define FEAT 512
#define SEM 300
#define CAT (FEAT + SEM)  // 812
#define HLD 304           // padded h leading dim (16B-aligned rows)

typedef __attribute__((ext_vector_type(8))) short bf16x8;
typedef __attribute__((ext_vector_type(4))) float f32x4;
typedef __attribute__((ext_vector_type(8))) unsigned short us8;
typedef __attribute__((ext_vector_type(4))) unsigned short us4;
typedef __attribute__((ext_vector_type(2))) unsigned short us2;
typedef unsigned short us;

__device__ __forceinline__ us f2bf(float x) {
    union { float f; unsigned int u; } v; v.f = x;
    unsigned int r = v.u + 0x7FFFu + ((v.u >> 16) & 1u);
    return (us)(r >> 16);
}
__device__ __forceinline__ float bf2f(us u) {
    union { unsigned int u; float f; } v; v.u = ((unsigned int)u) << 16;
    return v.f;
}

// =============== workspace byte offsets (all 16B aligned) ===============
constexpr long O_BWH   = 0L;            // 8*8000*512*2 = 65,536,000
constexpr long O_H     = 65536000L;     // 8*8000*304*2 = 38,912,000
constexpr long O_PROBS = 104448000L;    // 8*16*8000*2 = 2,048,000 (aliases w1t/w2t/qwT)
constexpr long O_W1T   = 104448000L;    // 320*320*2 = 204,800 (dead before k_norm)
constexpr long O_W2T   = 104652800L;    // 204,800
constexpr long O_QWT   = 104857600L;    // 512*832*2 = 851,968 (ends 105,709,568)
constexpr long O_WVST  = 106496000L;    // 512*512*2 = 524,288
constexpr long O_FCWT  = 107020288L;    // 524,288
constexpr long O_PQT   = 107544576L;    // 8*16*840*2 = 215,040
constexpr long O_PMAX  = 107759616L;    // 8*16*63*4 = 32,256
constexpr long O_PSUM  = 107791872L;    // 32,256
constexpr long O_RMAX  = 107824128L;    // 512
constexpr long O_RINV  = 107824640L;    // 512
constexpr long O_F     = 107825152L;
constexpr long O_MBW   = O_F;            // 16,384
constexpr long O_MH    = O_F + 16384;    // 9,600 (contiguous with mbw for memset)
constexpr long O_GV    = O_F + 25984;    // 16,384
constexpr long O_GS    = O_F + 42368;    // 9,600
constexpr long O_AVG   = O_F + 51968;    // 25,984
constexpr long O_PSEMT = O_F + 77952;    // 128*304*4 = 155,648
constexpr long O_SSCH  = O_F + 233600;   // 153,600
constexpr long O_SSC   = O_F + 387200;   // 153,600
constexpr long O_QTOT  = O_F + 540800;   // 262,144
constexpr long O_CC    = O_F + 802944;   // 512
constexpr long O_TMP   = O_SSCH;         // alias (dead)
constexpr long O_OV    = O_QTOT;         // alias (dead)
// end = O_F + 803,456 = 108,628,608 bytes

// =============== weight prep: bf16 transposes ===============
__global__ void k_prep(const float* __restrict__ w1, const float* __restrict__ w2,
                       const float* __restrict__ wqs, const float* __restrict__ wqss,
                       const float* __restrict__ wvs, const float* __restrict__ fcw,
                       us* __restrict__ w1t, us* __restrict__ w2t, us* __restrict__ qwT,
                       us* __restrict__ wvsT, us* __restrict__ fcwT) {
    long e = (long)blockIdx.x * 256 + threadIdx.x;
    switch (blockIdx.y) {
    case 0: if (e < 320 * 320) { int n = e / 320, k = e % 320;
            w1t[e] = f2bf((n < SEM && k < SEM) ? w1[(long)k * SEM + n] : 0.f); } break;
    case 1: if (e < 320 * 320) { int n = e / 320, k = e % 320;
            w2t[e] = f2bf((n < SEM && k < SEM) ? w2[(long)k * SEM + n] : 0.f); } break;
    case 2: if (e < 512 * 832) { int n = e / 832, k = e % 832;
            float v = 0.f;
            if (k < FEAT) v = wqs[(long)k * FEAT + n];
            else if (k < CAT) v = wqss[(long)(k - FEAT) * FEAT + n];
            qwT[e] = f2bf(v); } break;
    case 3: if (e < 512 * 512) { int n = e / 512, k = e % 512;
            wvsT[e] = f2bf(wvs[(long)k * FEAT + n]); } break;
    case 4: if (e < 512 * 512) { int n = e / 512, k = e % 512;
            fcwT[e] = f2bf(fcw[(long)k * FEAT + n]); } break;
    }
}

// =============== bw -> bf16 + column sums (1600 blocks) ===============
__global__ void k_cvt_bw(const float* __restrict__ bw, us* __restrict__ bwh,
                         float* __restrict__ mbw) {
    int b = blockIdx.x, ch = blockIdx.y;  // 200 chunks of 40 rows
    int t = threadIdx.x;
    int cg = t & 127, rs = t >> 7;
    long base = ((long)b * NBASE + (long)ch * 40) * FEAT;
    float s0 = 0.f, s1 = 0.f, s2 = 0.f, s3 = 0.f;
    for (int r = rs; r < 40; r += 2) {
        float4 v = *(const float4*)(bw + base + (long)r * FEAT + cg * 4);
        us4 u; u.x = f2bf(v.x); u.y = f2bf(v.y); u.z = f2bf(v.z); u.w = f2bf(v.w);
        *(us4*)(bwh + base + (long)r * FEAT + cg * 4) = u;
        s0 += v.x; s1 += v.y; s2 += v.z; s3 += v.w;
    }
    atomicAdd(&mbw[b * FEAT + cg * 4 + 0], s0);
    atomicAdd(&mbw[b * FEAT + cg * 4 + 1], s1);
    atomicAdd(&mbw[b * FEAT + cg * 4 + 2], s2);
    atomicAdd(&mbw[b * FEAT + cg * 4 + 3], s3);
}

// =============== h = leaky(bsm @ W1 + b1), BM=128, per-batch grid (63, NB) ===============
__global__ __launch_bounds__(256, 2) void k_hgemm_mfma(const float* __restrict__ X,
        const us* __restrict__ W1T, const float* __restrict__ b1,
        us* __restrict__ H, float* __restrict__ mh) {
    __shared__ char smem[128 * 304 * 2];  // 77,824 B (max of A+B phase and C phase)
    us (*As)[72] = (us(*)[72])smem;                    // 128*72*2 = 18,432
    us (*Bs)[72] = (us(*)[72])(smem + 18432);          // 320*72*2 = 46,080
    us (*Cs)[HLD] = (us(*)[HLD])smem;                  // epilogue alias
    const int b = blockIdx.y;
    const int bm = blockIdx.x * 128;  // rows within batch (0..8063)
    const int t = threadIdx.x;
    const int wv = t >> 6, lane = t & 63;
    const int m16 = lane & 15, q = lane >> 4;
    const long rowbase = (long)b * NBASE;
    f32x4 acc[8][5];
    #pragma unroll
    for (int i = 0; i < 8; ++i)
        #pragma unroll
        for (int j = 0; j < 5; ++j) acc[i][j] = (f32x4){0.f, 0.f, 0.f, 0.f};
    for (int ks = 0; ks < 5; ++ks) {
        const int k0 = ks * 64;
        #pragma unroll
        for (int it = 0; it < 8; ++it) {  // A: 128 rows x 16 float4 groups
            int c = t + it * 256;
            int row = c >> 4, j = c & 15;
            int gk = k0 + j * 4;
            float4 v = make_float4(0.f, 0.f, 0.f, 0.f);
            if (gk < SEM && bm + row < NBASE)
                v = *(const float4*)(X + (rowbase + bm + row) * SEM + gk);
            us4 u; u.x = f2bf(v.x); u.y = f2bf(v.y); u.z = f2bf(v.z); u.w = f2bf(v.w);
            *(us4*)(&As[row][j * 4]) = u;
        }
        #pragma unroll
        for (int it = 0; it < 10; ++it) {  // B: 320 rows x 8 int4 groups
            int c = t + it * 256;
            int n = c >> 3, j = c & 7;
            int4 v = *(const int4*)(W1T + (long)n * 320 + k0 + j * 8);
            *(int4*)(&Bs[n][j * 8]) = v;
        }
        __syncthreads();
        #pragma unroll
        for (int kc = 0; kc < 64; kc += 32) {
            bf16x8 a[8], bb[5];
            #pragma unroll
            for (int rt = 0; rt < 8; ++rt)
                a[rt] = *(const bf16x8*)(&As[rt * 16 + m16][kc + q * 8]);
            #pragma unroll
            for (int ct = 0; ct < 5; ++ct)
                bb[ct] = *(const bf16x8*)(&Bs[(wv * 5 + ct) * 16 + m16][kc + q * 8]);
            #pragma unroll
            for (int rt = 0; rt < 8; ++rt)
                #pragma unroll
                for (int ct = 0; ct < 5; ++ct)
                    acc[rt][ct] = __builtin_amdgcn_mfma_f32_16x16x32_bf16(a[rt], bb[ct], acc[rt][ct], 0, 0, 0);
        }
        __syncthreads();
    }
    // epilogue: bias + leaky, stash bf16 into Cs, fused column sums
    float csum[5] = {0.f, 0.f, 0.f, 0.f, 0.f};
    #pragma unroll
    for (int ct = 0; ct < 5; ++ct) {
        int col = (wv * 5 + ct) * 16 + m16;
        float bias = (col < SEM) ? b1[col] : 0.f;
        #pragma unroll
        for (int rt = 0; rt < 8; ++rt) {
            int rl = rt * 16 + q * 4;
            #pragma unroll
            for (int r = 0; r < 4; ++r) {
                float v = acc[rt][ct][r] + bias;
                v = v > 0.f ? v : 0.1f * v;
                if (col < SEM && bm + rl + r < NBASE) {
                    Cs[rl + r][col] = f2bf(v);
                    csum[ct] += v;
                }
            }
        }
    }
    if (t < 128) *(us4*)(&Cs[t][300]) = (us4){0, 0, 0, 0};  // zero pad cols
    #pragma unroll
    for (int ct = 0; ct < 5; ++ct) {
        float s = csum[ct];
        s += __shfl_xor(s, 16);
        s += __shfl_xor(s, 32);
        int col = (wv * 5 + ct) * 16 + m16;
        if (q == 0 && col < SEM) atomicAdd(&mh[b * SEM + col], s);
    }
    __syncthreads();
    for (int i = t; i < 128 * 76; i += 256) {
        int row = i / 76, j = i % 76;
        if (bm + row < NBASE)
            *(us4*)(H + (rowbase + bm + row) * HLD + j * 4) = *(const us4*)(&Cs[row][j * 4]);
    }
}

// =============== avg vector: [mean(bw) | mean(h)@w2 + b2] ===============
__global__ void k_avg(const float* __restrict__ mbw, const float* __restrict__ mh,
                      const float* __restrict__ w2, const float* __restrict__ b2,
                      float* __restrict__ avg) {
    int x = blockIdx.x, b = blockIdx.y, t = threadIdx.x;
    const float invN = 1.0f / NBASE;
    if (x == 5) {
        for (int i = t; i < FEAT; i += 256) avg[b * CAT + i] = mbw[b * FEAT + i] * invN;
        return;
    }
    __shared__ float mhL[SEM];
    __shared__ float red[4][64];
    for (int i = t; i < SEM; i += 256) mhL[i] = mh[b * SEM + i] * invN;
    __syncthreads();
    int s = x * 64 + (t & 63);
    int kq = t >> 6;
    float a = 0.f;
    if (s < SEM)
        for (int c = kq * 75; c < kq * 75 + 75; ++c) a += mhL[c] * w2[(long)c * SEM + s];
    red[kq][t & 63] = a;
    __syncthreads();
    if (kq == 0 && s < SEM)
        avg[b * CAT + FEAT + s] = red[0][t & 63] + red[1][t & 63] + red[2][t & 63] + red[3][t & 63] + b2[s];
}

// =============== gates matvec ===============
__global__ void k_gates_mv(const float* __restrict__ avg, const float* __restrict__ vfw,
                           const float* __restrict__ vfb, const float* __restrict__ sfw,
                           const float* __restrict__ sfb, float* __restrict__ gv,
                           float* __restrict__ gs) {
    int tile = blockIdx.x, b = blockIdx.y, t = threadIdx.x;
    __shared__ float avgL[CAT];
    __shared__ float red[4][64];
    for (int i = t; i < CAT; i += 256) avgL[i] = avg[b * CAT + i];
    __syncthreads();
    int l = t & 63, kq = t >> 6;
    float a = 0.f;
    if (tile < 8) {
        int f = tile * 64 + l;
        for (int c = kq * 203; c < kq * 203 + 203; ++c) a += avgL[c] * vfw[(long)c * FEAT + f];
        red[kq][l] = a;
        __syncthreads();
        if (kq == 0) {
            float s = red[0][l] + red[1][l] + red[2][l] + red[3][l] + vfb[f];
            gv[b * FEAT + f] = 1.f + 1.f / (1.f + expf(-s));
        }
    } else {
        int fs = (tile - 8) * 64 + l;
        if (fs < SEM)
            for (int c = kq * 203; c < kq * 203 + 203; ++c) a += avgL[c] * sfw[(long)c * SEM + fs];
        red[kq][l] = a;
        __syncthreads();
        if (kq == 0 && fs < SEM) {
            float s = red[0][l] + red[1][l] + red[2][l] + red[3][l] + sfb[fs];
            gs[b * SEM + fs] = 1.f + 1.f / (1.f + expf(-s));
        }
    }
}

// =============== generic M=128 MFMA GEMM, 8 modes ===============
constexpr int MM_K[8]    = {300, 300, 812, 512, 512, 300, 512, 512};
constexpr int MM_K1[8]   = {300, 300, 512, 512, 512, 300, 512, 512};
constexpr int MM_KP[8]   = {320, 320, 832, 512, 512, 320, 512, 512};
constexpr int MM_N[8]    = {300, 300, 512, 512, 300, 300, 512, 512};
constexpr int MM_LDB[8]  = {320, 320, 832, 512, 512, 300, 512, 512};
constexpr int MM_LDA0[8] = {300, 300, 512, 512, 512, 304, 512, 512};
constexpr bool MM_BBF[8] = {true, true, true, false, false, false, true, true};

template <int MODE>
__global__ __launch_bounds__(256) void k_mm(const float* __restrict__ A0,
        const float* __restrict__ A1, const void* __restrict__ Bv,
        const float* __restrict__ bias, const float* __restrict__ gate,
        const float* __restrict__ res, float* __restrict__ Cf, us* __restrict__ Cb) {
    constexpr int K = MM_K[MODE], K1 = MM_K1[MODE], KP = MM_KP[MODE];
    constexpr int N = MM_N[MODE], LDB = MM_LDB[MODE], LDA0 = MM_LDA0[MODE];
    __shared__ us As[128][40];
    __shared__ us Bs[64][40];
    const int n0 = blockIdx.x * 64;
    const int t = threadIdx.x;
    const int wv = t >> 6, lane = t & 63;
    const int m16 = lane & 15, q = lane >> 4;
    const int wm = wv >> 1, wn = wv & 1;
    f32x4 acc[4][2];
    #pragma unroll
    for (int i = 0; i < 4; ++i) { acc[i][0] = (f32x4){0,0,0,0}; acc[i][1] = (f32x4){0,0,0,0}; }
    for (int ks = 0; ks < KP / 32; ++ks) {
        const int k0 = ks * 32;
        #pragma unroll
        for (int it = 0; it < 4; ++it) {
            int idx = t + it * 256;
            int row = idx >> 3, j = idx & 7;
            int gk = k0 + j * 4;
            float4 v = make_float4(0.f, 0.f, 0.f, 0.f);
            if (gk < K1) v = *(const float4*)(A0 + (long)row * LDA0 + gk);
            else if constexpr (K1 < K) {
                if (gk < K) v = *(const float4*)(A1 + (long)row * 300 + (gk - K1));
            }
            us4 u; u.x = f2bf(v.x); u.y = f2bf(v.y); u.z = f2bf(v.z); u.w = f2bf(v.w);
            *(us4*)(&As[row][j * 4]) = u;
        }
        if constexpr (MM_BBF[MODE]) {
            int n = t >> 2, j = t & 3;
            *(int4*)(&Bs[n][j * 8]) = *(const int4*)((const us*)Bv + (long)(n0 + n) * LDB + k0 + j * 8);
        } else {
            #pragma unroll
            for (int it = 0; it < 2; ++it) {
                int idx = t + it * 256;
                int n = idx >> 3, j = idx & 7;
                int gk = k0 + j * 4;
                float4 v = make_float4(0.f, 0.f, 0.f, 0.f);
                if ((N == 512 || n0 + n < N) && gk < K)
                    v = *(const float4*)((const float*)Bv + (long)(n0 + n) * LDB + gk);
                us4 u; u.x = f2bf(v.x); u.y = f2bf(v.y); u.z = f2bf(v.z); u.w = f2bf(v.w);
                *(us4*)(&Bs[n][j * 4]) = u;
            }
        }
        __syncthreads();
        bf16x8 a[4], bb[2];
        #pragma unroll
        for (int rt = 0; rt < 4; ++rt) a[rt] = *(const bf16x8*)(&As[wm * 64 + rt * 16 + m16][q * 8]);
        #pragma unroll
        for (int ct = 0; ct < 2; ++ct) bb[ct] = *(const bf16x8*)(&Bs[wn * 32 + ct * 16 + m16][q * 8]);
        #pragma unroll
        for (int rt = 0; rt < 4; ++rt)
            #pragma unroll
            for (int ct = 0; ct < 2; ++ct)
                acc[rt][ct] = __builtin_amdgcn_mfma_f32_16x16x32_bf16(a[rt], bb[ct], acc[rt][ct], 0, 0, 0);
        __syncthreads();
    }
    #pragma unroll
    for (int rt = 0; rt < 4; ++rt) {
        #pragma unroll
        for (int ct = 0; ct < 2; ++ct) {
            int col = n0 + wn * 32 + ct * 16 + m16;
            if (N != 512 && col >= N) continue;
            #pragma unroll
            for (int r = 0; r < 4; ++r) {
                int row = wm * 64 + rt * 16 + q * 4 + r;
                float v = acc[rt][ct][r];
                if constexpr (MODE == 0) {
                    v += bias[col]; v = v > 0.f ? v : 0.1f * v;
                    Cf[(long)row * 300 + col] = v;
                } else if constexpr (MODE == 1) {
                    Cf[(long)row * 300 + col] = v + bias[col];
                } else if constexpr (MODE == 2 || MODE == 6) {
                    Cf[(long)row * 512 + col] = v;
                } else if constexpr (MODE == 3) {
                    Cb[(long)row * 840 + col] = f2bf(gate[(row >> 4) * FEAT + col] * v);
                } else if constexpr (MODE == 4) {
                    Cf[(long)row * HLD + col] = gate[(row >> 4) * SEM + col] * v;
                } else if constexpr (MODE == 5) {
                    Cb[(long)row * 840 + 512 + col] = f2bf(v);
                } else if constexpr (MODE == 7) {
                    Cf[(long)row * 512 + col] = v + res[(long)row * 512 + col];
                }
            }
        }
    }
}

// =============== cconst[b,w] = psemT[b*16+w] . b2 ===============
__global__ void k_cconst(const float* __restrict__ psemT, const float* __restrict__ b2,
                         float* __restrict__ cconst) {
    int b = blockIdx.x, t = threadIdx.x;
    int w = t >> 4, l = t & 15;
    float a = 0.f;
    for (int s = l; s < SEM; s += 16) a += psemT[(long)(b * NWAY + w) * HLD + s] * b2[s];
    a += __shfl_xor(a, 1); a += __shfl_xor(a, 2);
    a += __shfl_xor(a, 4); a += __shfl_xor(a, 8);
    if (l == 0) cconst[b * NWAY + w] = a;
}

// =============== scores + fused per-block softmax partials ===============
__global__ __launch_bounds__(256) void k_scores_mfma(const us* __restrict__ bwh,
        const us* __restrict__ h, const us* __restrict__ pqt,
        const float* __restrict__ cconst, float* __restrict__ scores,
        float* __restrict__ pmax, float* __restrict__ psum) {
    __shared__ us As[128][40];
    __shared__ us Bs[NWAY][840];
    __shared__ float sred[4][16];
    const int b = blockIdx.y;
    const int bm = blockIdx.x * 128;
    const int t = threadIdx.x;
    const int wv = t >> 6, lane = t & 63;
    const int m16 = lane & 15, q = lane >> 4;
    for (int c = t; c < NWAY * 105; c += 256) {
        int n = c / 105, j = c % 105;
        *(int4*)(&Bs[n][j * 8]) = *(const int4*)(pqt + ((long)b * NWAY + n) * 840 + j * 8);
    }
    f32x4 acc[2];
    acc[0] = (f32x4){0,0,0,0};
    acc[1] = (f32x4){0,0,0,0};
    for (int ks = 0; ks < 26; ++ks) {
        int k0 = ks * 32;
        #pragma unroll
        for (int it = 0; it < 2; ++it) {  // A: 128 rows x 4 us8 groups (16B loads)
            int c = t + it * 256;
            int row = c >> 2, j = c & 3;
            int gm = bm + row, gk = k0 + j * 8;
            us8 u = (us8){0, 0, 0, 0, 0, 0, 0, 0};
            if (gk < FEAT)      u = *(const us8*)(bwh + ((long)b * NBASE + gm) * FEAT + gk);
            else if (gk < CAT)  u = *(const us8*)(h + ((long)b * NBASE + gm) * HLD + (gk - FEAT));
            *(us8*)(&As[row][j * 8]) = u;
        }
        __syncthreads();
        bf16x8 bb = *(const bf16x8*)(&Bs[m16][k0 + q * 8]);
        #pragma unroll
        for (int rt = 0; rt < 2; ++rt) {
            bf16x8 a = *(const bf16x8*)(&As[wv * 32 + rt * 16 + m16][q * 8]);
            acc[rt] = __builtin_amdgcn_mfma_f32_16x16x32_bf16(a, bb, acc[rt], 0, 0, 0);
        }
        __syncthreads();
    }
    const float invT = 0.04419417382415922f;  // 1/sqrt(512)
    float cadd = cconst[b * NWAY + m16];
    float vals[8];
    #pragma unroll
    for (int rt = 0; rt < 2; ++rt) {
        int nrow = bm + wv * 32 + rt * 16 + q * 4;
        #pragma unroll
        for (int r = 0; r < 4; ++r) {
            float v = (nrow + r < NBASE) ? (acc[rt][r] + cadd) * invT : -1e30f;
            vals[rt * 4 + r] = v;
        }
        if (nrow + 3 < NBASE) {
            float4 st = make_float4(vals[rt * 4], vals[rt * 4 + 1], vals[rt * 4 + 2], vals[rt * 4 + 3]);
            *(float4*)(scores + ((long)b * NWAY + m16) * NBASE + nrow) = st;
        } else {
            for (int r = 0; r < 4; ++r)
                if (nrow + r < NBASE)
                    scores[((long)b * NWAY + m16) * NBASE + nrow + r] = vals[rt * 4 + r];
        }
    }
    // block max per w
    float lm = vals[0];
    #pragma unroll
    for (int i = 1; i < 8; ++i) lm = fmaxf(lm, vals[i]);
    lm = fmaxf(lm, __shfl_xor(lm, 16));
    lm = fmaxf(lm, __shfl_xor(lm, 32));
    if (q == 0) sred[wv][m16] = lm;
    __syncthreads();
    float bmax = fmaxf(fmaxf(sred[0][m16], sred[1][m16]), fmaxf(sred[2][m16], sred[3][m16]));
    __syncthreads();
    // block sumexp per w
    float ls = 0.f;
    #pragma unroll
    for (int i = 0; i < 8; ++i) ls += __expf(vals[i] - bmax);
    ls += __shfl_xor(ls, 16);
    ls += __shfl_xor(ls, 32);
    if (q == 0) sred[wv][m16] = ls;
    __syncthreads();
    if (wv == 0 && lane < 16) {
        float tot = sred[0][m16] + sred[1][m16] + sred[2][m16] + sred[3][m16];
        pmax[((long)b * NWAY + m16) * 63 + blockIdx.x] = bmax;
        psum[((long)b * NWAY + m16) * 63 + blockIdx.x] = tot;
    }
}

// =============== combine partials -> row max & 1/sum ===============
__global__ void k_combine(const float* __restrict__ pmax, const float* __restrict__ psum,
                          float* __restrict__ rmax, float* __restrict__ rinv) {
    int b = blockIdx.x, t = threadIdx.x;
    int w = t >> 4, l = t & 15;
    long base = ((long)b * NWAY + w) * 63;
    float m = -1e30f;
    for (int i = l; i < 63; i += 16) m = fmaxf(m, pmax[base + i]);
    m = fmaxf(m, __shfl_xor(m, 1)); m = fmaxf(m, __shfl_xor(m, 2));
    m = fmaxf(m, __shfl_xor(m, 4)); m = fmaxf(m, __shfl_xor(m, 8));
    float s = 0.f;
    for (int i = l; i < 63; i += 16) s += psum[base + i] * __expf(pmax[base + i] - m);
    s += __shfl_xor(s, 1); s += __shfl_xor(s, 2);
    s += __shfl_xor(s, 4); s += __shfl_xor(s, 8);
    if (l == 0) { rmax[b * NWAY + w] = m; rinv[b * NWAY + w] = 1.0f / s; }
}

// =============== normalize: probs = exp(score - M) * inv, bf16 ===============
__global__ void k_norm(const float* __restrict__ scores, const float* __restrict__ rmax,
                       const float* __restrict__ rinv, us* __restrict__ probsb) {
    int b = blockIdx.y;
    int bm = blockIdx.x * 128;
    int t = threadIdx.x;
    for (int i = t; i < NWAY * 128; i += 256) {
        int w = i >> 7, j = i & 127;
        int n = bm + j;
        if (n < NBASE) {
            long idx = ((long)b * NWAY + w) * NBASE + n;
            float v = __expf(scores[idx] - rmax[b * NWAY + w]) * rinv[b * NWAY + w];
            probsb[idx] = f2bf(v);
        }
    }
}

// =============== ov = probs @ bwh (512 blocks, fp32 atomics) ===============
__global__ void k_ov(const us* __restrict__ probsb, const us* __restrict__ bwh,
                     float* __restrict__ ov) {
    int b = blockIdx.x, ch = blockIdx.y;  // 64 chunks of 125 rows
    int t = threadIdx.x;
    __shared__ float pr[NWAY][125];
    for (int i = t; i < NWAY * 125; i += 256) {
        int w = i / 125, j = i % 125;
        pr[w][j] = bf2f(probsb[((long)b * NWAY + w) * NBASE + (long)ch * 125 + j]);
    }
    __syncthreads();
    float a0[NWAY], a1[NWAY];
    #pragma unroll
    for (int w = 0; w < NWAY; ++w) { a0[w] = 0.f; a1[w] = 0.f; }
    const us* bp = bwh + ((long)b * NBASE + (long)ch * 125) * FEAT + 2 * t;
    #pragma unroll 5
    for (int j = 0; j < 125; ++j) {
        us2 u = *(const us2*)(bp + (long)j * FEAT);
        float v0 = bf2f(u.x), v1 = bf2f(u.y);
        #pragma unroll
        for (int w = 0; w < NWAY; ++w) {
            a0[w] += pr[w][j] * v0;
            a1[w] += pr[w][j] * v1;
        }
    }
    for (int w = 0; w < NWAY; ++w) {
        atomicAdd(&ov[((long)b * NWAY + w) * FEAT + 2 * t], a0[w]);
        atomicAdd(&ov[((long)b * NWAY + w) * FEAT + 2 * t + 1], a1[w]);
    }
}

extern "C" void kernel_launch(void* const* d_in, const int* in_sizes, int n_in,
                              void* d_out, int out_size, void* d_ws, size_t ws_size,
                              hipStream_t stream) {
    (void)in_sizes; (void)n_in; (void)out_size; (void)ws_size;
    const float* sf   = (const float*)d_in[0];
    const float* bw   = (const float*)d_in[1];
    const float* ssm  = (const float*)d_in[2];
    const float* bsm  = (const float*)d_in[3];
    const float* mw1  = (const float*)d_in[4];
    const float* mb1  = (const float*)d_in[5];
    const float* mw2  = (const float*)d_in[6];
    const float* mb2  = (const float*)d_in[7];
    const float* vfw  = (const float*)d_in[8];
    const float* vfb  = (const float*)d_in[9];
    const float* sfw  = (const float*)d_in[10];
    const float* sfb  = (const float*)d_in[11];
    const float* wqs  = (const float*)d_in[12];
    const float* wks  = (const float*)d_in[13];
    const float* wvs  = (const float*)d_in[14];
    const float* wqss = (const float*)d_in[15];
    const float* wkss = (const float*)d_in[16];
    const float* fcw  = (const float*)d_in[17];

    float* out = (float*)d_out;
    float* scores = out + NB * NWAY * FEAT;  // d_out = [out | attn_score]

    char* wsb = (char*)d_ws;
    us* bwh    = (us*)(wsb + O_BWH);
    us* h      = (us*)(wsb + O_H);
    us* probsb = (us*)(wsb + O_PROBS);
    us* w1t    = (us*)(wsb + O_W1T);
    us* w2t    = (us*)(wsb + O_W2T);
    us* qwT    = (us*)(wsb + O_QWT);
    us* wvsT   = (us*)(wsb + O_WVST);
    us* fcwT   = (us*)(wsb + O_FCWT);
    us* pqt    = (us*)(wsb + O_PQT);
    float* pmax   = (float*)(wsb + O_PMAX);
    float* psum   = (float*)(wsb + O_PSUM);
    float* rmax   = (float*)(wsb + O_RMAX);
    float* rinv   = (float*)(wsb + O_RINV);
    float* mbw    = (float*)(wsb + O_MBW);
    float* mh     = (float*)(wsb + O_MH);
    float* gv     = (float*)(wsb + O_GV);
    float* gs     = (float*)(wsb + O_GS);
    float* avgv   = (float*)(wsb + O_AVG);
    float* psemT  = (float*)(wsb + O_PSEMT);
    float* sscH   = (float*)(wsb + O_SSCH);
    float* ssc    = (float*)(wsb + O_SSC);
    float* qtot   = (float*)(wsb + O_QTOT);
    float* cconst = (float*)(wsb + O_CC);
    float* tmp    = (float*)(wsb + O_TMP);
    float* ov     = (float*)(wsb + O_OV);

    hipMemsetAsync(mbw, 0, (NB * FEAT + NB * SEM) * sizeof(float), stream);  // mbw+mh
    hipMemsetAsync(pqt, 0, (long)NB * NWAY * 840 * 2, stream);               // zero pads

    k_prep<<<dim3(1664, 5), 256, 0, stream>>>(mw1, mw2, wqs, wqss, wvs, fcw, w1t, w2t, qwT, wvsT, fcwT);
    k_cvt_bw<<<dim3(NB, 200), 256, 0, stream>>>(bw, bwh, mbw);
    k_hgemm_mfma<<<dim3(63, NB), 256, 0, stream>>>(bsm, w1t, mb1, h, mh);
    k_avg<<<dim3(6, NB), 256, 0, stream>>>(mbw, mh, mw2, mb2, avgv);
    k_gates_mv<<<dim3(13, NB), 256, 0, stream>>>(avgv, vfw, vfb, sfw, sfb, gv, gs);
    k_mm<0><<<5, 256, 0, stream>>>(ssm, nullptr, w1t, mb1, nullptr, nullptr, sscH, nullptr);
    k_mm<1><<<5, 256, 0, stream>>>(sscH, nullptr, w2t, mb2, nullptr, nullptr, ssc, nullptr);
    k_mm<2><<<8, 256, 0, stream>>>(sf, ssc, qwT, nullptr, nullptr, nullptr, qtot, nullptr);
    k_mm<3><<<8, 256, 0, stream>>>(qtot, nullptr, wks, nullptr, gv, nullptr, nullptr, pqt);
    k_mm<4><<<5, 256, 0, stream>>>(qtot, nullptr, wkss, nullptr, gs, nullptr, psemT, nullptr);
    k_mm<5><<<5, 256, 0, stream>>>(psemT, nullptr, mw2, nullptr, nullptr, nullptr, nullptr, pqt);
    k_cconst<<<NB, 256, 0, stream>>>(psemT, mb2, cconst);
    k_scores_mfma<<<dim3(63, NB), 256, 0, stream>>>(bwh, h, pqt, cconst, scores, pmax, psum);
    k_combine<<<NB, 256, 0, stream>>>(pmax, psum, rmax, rinv);
    k_norm<<<dim3(63, NB), 256, 0, stream>>>(scores, rmax, rinv, probsb);
    hipMemsetAsync(ov, 0, NB * NWAY * FEAT * sizeof(float), stream);
    k_ov<<<dim3(NB, 64), 256, 0, stream>>>(probsb, bwh, ov);
    k_mm<6><<<8, 256, 0, stream>>>(ov, nullptr, wvsT, nullptr, nullptr, nullptr, tmp, nullptr);
    k_mm<7><<<8, 256, 0, stream>>>(tmp, nullptr, fcwT, nullptr, nullptr, sf, out, nullptr);
}

// Round 5
// 651.255 us; speedup vs baseline: 1.9913x; 1.0669x over previous
//
#include <hip/hip_runtime.h>

#define NB 8
#define NWAY 16
#define NBASE 8000
#define FEAT 512
#define SEM 300
#define CAT (FEAT + SEM)  // 812
#define HLD 304           // padded h leading dim (16B-aligned rows)

typedef __attribute__((ext_vector_type(8))) short bf16x8;
typedef __attribute__((ext_vector_type(4))) float f32x4;
typedef __attribute__((ext_vector_type(8))) unsigned short us8;
typedef __attribute__((ext_vector_type(4))) unsigned short us4;
typedef __attribute__((ext_vector_type(2))) unsigned short us2;
typedef unsigned short us;

__device__ __forceinline__ us f2bf(float x) {
    union { float f; unsigned int u; } v; v.f = x;
    unsigned int r = v.u + 0x7FFFu + ((v.u >> 16) & 1u);
    return (us)(r >> 16);
}
__device__ __forceinline__ float bf2f(us u) {
    union { unsigned int u; float f; } v; v.u = ((unsigned int)u) << 16;
    return v.f;
}

// =============== workspace byte offsets (all 16B aligned) ===============
constexpr long O_BWH   = 0L;            // 8*8000*512*2 = 65,536,000
constexpr long O_H     = 65536000L;     // 8*8000*304*2 = 38,912,000
constexpr long O_W1T   = 104448000L;    // 320*320*2 = 204,800
constexpr long O_W2T   = 104652800L;    // 204,800
constexpr long O_QWT   = 104857600L;    // 512*832*2 = 851,968
constexpr long O_WVST  = 106496000L;    // 512*512*2 = 524,288
constexpr long O_FCWT  = 107020288L;    // 524,288
constexpr long O_PQT   = 107544576L;    // 8*16*840*2 = 215,040
constexpr long O_PMAX  = 107759616L;    // 8*16*63*4 = 32,256
constexpr long O_PSUM  = 107791872L;    // 32,256
constexpr long O_RMAX  = 107824128L;    // 512
constexpr long O_RINV  = 107824640L;    // 512
constexpr long O_F     = 107825152L;
constexpr long O_MBW   = O_F;            // 16,384
constexpr long O_MH    = O_F + 16384;    // 9,600 (contiguous with mbw for memset)
constexpr long O_GV    = O_F + 25984;    // 16,384
constexpr long O_GS    = O_F + 42368;    // 9,600
constexpr long O_AVG   = O_F + 51968;    // 25,984
constexpr long O_PSEMT = O_F + 77952;    // 128*304*4 = 155,648
constexpr long O_SSCH  = O_F + 233600;   // 153,600
constexpr long O_SSC   = O_F + 387200;   // 153,600
constexpr long O_QTOT  = O_F + 540800;   // 262,144
constexpr long O_CC    = O_F + 802944;   // 512
constexpr long O_TMP   = O_SSCH;         // alias (dead)
constexpr long O_OV    = O_QTOT;         // alias (dead)

// =============== weight prep: bf16 transposes ===============
__global__ void k_prep(const float* __restrict__ w1, const float* __restrict__ w2,
                       const float* __restrict__ wqs, const float* __restrict__ wqss,
                       const float* __restrict__ wvs, const float* __restrict__ fcw,
                       us* __restrict__ w1t, us* __restrict__ w2t, us* __restrict__ qwT,
                       us* __restrict__ wvsT, us* __restrict__ fcwT) {
    long e = (long)blockIdx.x * 256 + threadIdx.x;
    switch (blockIdx.y) {
    case 0: if (e < 320 * 320) { int n = e / 320, k = e % 320;
            w1t[e] = f2bf((n < SEM && k < SEM) ? w1[(long)k * SEM + n] : 0.f); } break;
    case 1: if (e < 320 * 320) { int n = e / 320, k = e % 320;
            w2t[e] = f2bf((n < SEM && k < SEM) ? w2[(long)k * SEM + n] : 0.f); } break;
    case 2: if (e < 512 * 832) { int n = e / 832, k = e % 832;
            float v = 0.f;
            if (k < FEAT) v = wqs[(long)k * FEAT + n];
            else if (k < CAT) v = wqss[(long)(k - FEAT) * FEAT + n];
            qwT[e] = f2bf(v); } break;
    case 3: if (e < 512 * 512) { int n = e / 512, k = e % 512;
            wvsT[e] = f2bf(wvs[(long)k * FEAT + n]); } break;
    case 4: if (e < 512 * 512) { int n = e / 512, k = e % 512;
            fcwT[e] = f2bf(fcw[(long)k * FEAT + n]); } break;
    }
}

// =============== bw -> bf16 + column sums: unroll-4 MLP, LDS-reduced atomics ===============
__global__ void k_cvt_bw(const float* __restrict__ bw, us* __restrict__ bwh,
                         float* __restrict__ mbw) {
    __shared__ float red[128][4];
    int b = blockIdx.x, ch = blockIdx.y;  // 125 chunks of 64 rows
    int t = threadIdx.x;
    int cg = t & 127, rs = t >> 7;
    long base = ((long)b * NBASE + (long)ch * 64) * FEAT + cg * 4;
    float s0 = 0.f, s1 = 0.f, s2 = 0.f, s3 = 0.f;
    for (int r0 = rs * 4; r0 < 64; r0 += 8) {
        float4 v[4];
        #pragma unroll
        for (int u = 0; u < 4; ++u)
            v[u] = *(const float4*)(bw + base + (long)(r0 + u) * FEAT);
        #pragma unroll
        for (int u = 0; u < 4; ++u) {
            us4 o; o.x = f2bf(v[u].x); o.y = f2bf(v[u].y); o.z = f2bf(v[u].z); o.w = f2bf(v[u].w);
            *(us4*)(bwh + base + (long)(r0 + u) * FEAT) = o;
            s0 += v[u].x; s1 += v[u].y; s2 += v[u].z; s3 += v[u].w;
        }
    }
    if (rs == 1) { red[cg][0] = s0; red[cg][1] = s1; red[cg][2] = s2; red[cg][3] = s3; }
    __syncthreads();
    if (rs == 0) {
        atomicAdd(&mbw[b * FEAT + cg * 4 + 0], s0 + red[cg][0]);
        atomicAdd(&mbw[b * FEAT + cg * 4 + 1], s1 + red[cg][1]);
        atomicAdd(&mbw[b * FEAT + cg * 4 + 2], s2 + red[cg][2]);
        atomicAdd(&mbw[b * FEAT + cg * 4 + 3], s3 + red[cg][3]);
    }
}

// =============== h = leaky(bsm @ W1 + b1), BM=128, per-batch grid (63, NB) ===============
__global__ __launch_bounds__(256, 2) void k_hgemm_mfma(const float* __restrict__ X,
        const us* __restrict__ W1T, const float* __restrict__ b1,
        us* __restrict__ H, float* __restrict__ mh) {
    __shared__ char smem[128 * 304 * 2];  // 77,824 B
    us (*As)[72] = (us(*)[72])smem;                    // 128*72*2 = 18,432
    us (*Bs)[72] = (us(*)[72])(smem + 18432);          // 320*72*2 = 46,080
    us (*Cs)[HLD] = (us(*)[HLD])smem;                  // epilogue alias
    const int b = blockIdx.y;
    const int bm = blockIdx.x * 128;
    const int t = threadIdx.x;
    const int wv = t >> 6, lane = t & 63;
    const int m16 = lane & 15, q = lane >> 4;
    const long rowbase = (long)b * NBASE;
    f32x4 acc[8][5];
    #pragma unroll
    for (int i = 0; i < 8; ++i)
        #pragma unroll
        for (int j = 0; j < 5; ++j) acc[i][j] = (f32x4){0.f, 0.f, 0.f, 0.f};
    for (int ks = 0; ks < 5; ++ks) {
        const int k0 = ks * 64;
        #pragma unroll
        for (int it = 0; it < 8; ++it) {
            int c = t + it * 256;
            int row = c >> 4, j = c & 15;
            int gk = k0 + j * 4;
            float4 v = make_float4(0.f, 0.f, 0.f, 0.f);
            if (gk < SEM && bm + row < NBASE)
                v = *(const float4*)(X + (rowbase + bm + row) * SEM + gk);
            us4 u; u.x = f2bf(v.x); u.y = f2bf(v.y); u.z = f2bf(v.z); u.w = f2bf(v.w);
            *(us4*)(&As[row][j * 4]) = u;
        }
        #pragma unroll
        for (int it = 0; it < 10; ++it) {
            int c = t + it * 256;
            int n = c >> 3, j = c & 7;
            int4 v = *(const int4*)(W1T + (long)n * 320 + k0 + j * 8);
            *(int4*)(&Bs[n][j * 8]) = v;
        }
        __syncthreads();
        #pragma unroll
        for (int kc = 0; kc < 64; kc += 32) {
            bf16x8 a[8], bb[5];
            #pragma unroll
            for (int rt = 0; rt < 8; ++rt)
                a[rt] = *(const bf16x8*)(&As[rt * 16 + m16][kc + q * 8]);
            #pragma unroll
            for (int ct = 0; ct < 5; ++ct)
                bb[ct] = *(const bf16x8*)(&Bs[(wv * 5 + ct) * 16 + m16][kc + q * 8]);
            #pragma unroll
            for (int rt = 0; rt < 8; ++rt)
                #pragma unroll
                for (int ct = 0; ct < 5; ++ct)
                    acc[rt][ct] = __builtin_amdgcn_mfma_f32_16x16x32_bf16(a[rt], bb[ct], acc[rt][ct], 0, 0, 0);
        }
        __syncthreads();
    }
    float csum[5] = {0.f, 0.f, 0.f, 0.f, 0.f};
    #pragma unroll
    for (int ct = 0; ct < 5; ++ct) {
        int col = (wv * 5 + ct) * 16 + m16;
        float bias = (col < SEM) ? b1[col] : 0.f;
        #pragma unroll
        for (int rt = 0; rt < 8; ++rt) {
            int rl = rt * 16 + q * 4;
            #pragma unroll
            for (int r = 0; r < 4; ++r) {
                float v = acc[rt][ct][r] + bias;
                v = v > 0.f ? v : 0.1f * v;
                if (col < SEM && bm + rl + r < NBASE) {
                    Cs[rl + r][col] = f2bf(v);
                    csum[ct] += v;
                }
            }
        }
    }
    if (t < 128) *(us4*)(&Cs[t][300]) = (us4){0, 0, 0, 0};
    #pragma unroll
    for (int ct = 0; ct < 5; ++ct) {
        float s = csum[ct];
        s += __shfl_xor(s, 16);
        s += __shfl_xor(s, 32);
        int col = (wv * 5 + ct) * 16 + m16;
        if (q == 0 && col < SEM) atomicAdd(&mh[b * SEM + col], s);
    }
    __syncthreads();
    for (int i = t; i < 128 * 76; i += 256) {
        int row = i / 76, j = i % 76;
        if (bm + row < NBASE)
            *(us4*)(H + (rowbase + bm + row) * HLD + j * 4) = *(const us4*)(&Cs[row][j * 4]);
    }
}

// =============== avg vector: [mean(bw) | mean(h)@w2 + b2] ===============
__global__ void k_avg(const float* __restrict__ mbw, const float* __restrict__ mh,
                      const float* __restrict__ w2, const float* __restrict__ b2,
                      float* __restrict__ avg) {
    int x = blockIdx.x, b = blockIdx.y, t = threadIdx.x;
    const float invN = 1.0f / NBASE;
    if (x == 5) {
        for (int i = t; i < FEAT; i += 256) avg[b * CAT + i] = mbw[b * FEAT + i] * invN;
        return;
    }
    __shared__ float mhL[SEM];
    __shared__ float red[4][64];
    for (int i = t; i < SEM; i += 256) mhL[i] = mh[b * SEM + i] * invN;
    __syncthreads();
    int s = x * 64 + (t & 63);
    int kq = t >> 6;
    float a = 0.f;
    if (s < SEM)
        for (int c = kq * 75; c < kq * 75 + 75; ++c) a += mhL[c] * w2[(long)c * SEM + s];
    red[kq][t & 63] = a;
    __syncthreads();
    if (kq == 0 && s < SEM)
        avg[b * CAT + FEAT + s] = red[0][t & 63] + red[1][t & 63] + red[2][t & 63] + red[3][t & 63] + b2[s];
}

// =============== gates matvec ===============
__global__ void k_gates_mv(const float* __restrict__ avg, const float* __restrict__ vfw,
                           const float* __restrict__ vfb, const float* __restrict__ sfw,
                           const float* __restrict__ sfb, float* __restrict__ gv,
                           float* __restrict__ gs) {
    int tile = blockIdx.x, b = blockIdx.y, t = threadIdx.x;
    __shared__ float avgL[CAT];
    __shared__ float red[4][64];
    for (int i = t; i < CAT; i += 256) avgL[i] = avg[b * CAT + i];
    __syncthreads();
    int l = t & 63, kq = t >> 6;
    float a = 0.f;
    if (tile < 8) {
        int f = tile * 64 + l;
        for (int c = kq * 203; c < kq * 203 + 203; ++c) a += avgL[c] * vfw[(long)c * FEAT + f];
        red[kq][l] = a;
        __syncthreads();
        if (kq == 0) {
            float s = red[0][l] + red[1][l] + red[2][l] + red[3][l] + vfb[f];
            gv[b * FEAT + f] = 1.f + 1.f / (1.f + expf(-s));
        }
    } else {
        int fs = (tile - 8) * 64 + l;
        if (fs < SEM)
            for (int c = kq * 203; c < kq * 203 + 203; ++c) a += avgL[c] * sfw[(long)c * SEM + fs];
        red[kq][l] = a;
        __syncthreads();
        if (kq == 0 && fs < SEM) {
            float s = red[0][l] + red[1][l] + red[2][l] + red[3][l] + sfb[fs];
            gs[b * SEM + fs] = 1.f + 1.f / (1.f + expf(-s));
        }
    }
}

// =============== generic M=128 MFMA GEMM, 8 modes ===============
constexpr int MM_K[8]    = {300, 300, 812, 512, 512, 300, 512, 512};
constexpr int MM_K1[8]   = {300, 300, 512, 512, 512, 300, 512, 512};
constexpr int MM_KP[8]   = {320, 320, 832, 512, 512, 320, 512, 512};
constexpr int MM_N[8]    = {300, 300, 512, 512, 300, 300, 512, 512};
constexpr int MM_LDB[8]  = {320, 320, 832, 512, 512, 300, 512, 512};
constexpr int MM_LDA0[8] = {300, 300, 512, 512, 512, 304, 512, 512};
constexpr bool MM_BBF[8] = {true, true, true, false, false, false, true, true};

template <int MODE>
__global__ __launch_bounds__(256) void k_mm(const float* __restrict__ A0,
        const float* __restrict__ A1, const void* __restrict__ Bv,
        const float* __restrict__ bias, const float* __restrict__ gate,
        const float* __restrict__ res, float* __restrict__ Cf, us* __restrict__ Cb) {
    constexpr int K = MM_K[MODE], K1 = MM_K1[MODE], KP = MM_KP[MODE];
    constexpr int N = MM_N[MODE], LDB = MM_LDB[MODE], LDA0 = MM_LDA0[MODE];
    __shared__ us As[128][40];
    __shared__ us Bs[64][40];
    const int n0 = blockIdx.x * 64;
    const int t = threadIdx.x;
    const int wv = t >> 6, lane = t & 63;
    const int m16 = lane & 15, q = lane >> 4;
    const int wm = wv >> 1, wn = wv & 1;
    f32x4 acc[4][2];
    #pragma unroll
    for (int i = 0; i < 4; ++i) { acc[i][0] = (f32x4){0,0,0,0}; acc[i][1] = (f32x4){0,0,0,0}; }
    for (int ks = 0; ks < KP / 32; ++ks) {
        const int k0 = ks * 32;
        #pragma unroll
        for (int it = 0; it < 4; ++it) {
            int idx = t + it * 256;
            int row = idx >> 3, j = idx & 7;
            int gk = k0 + j * 4;
            float4 v = make_float4(0.f, 0.f, 0.f, 0.f);
            if (gk < K1) v = *(const float4*)(A0 + (long)row * LDA0 + gk);
            else if constexpr (K1 < K) {
                if (gk < K) v = *(const float4*)(A1 + (long)row * 300 + (gk - K1));
            }
            us4 u; u.x = f2bf(v.x); u.y = f2bf(v.y); u.z = f2bf(v.z); u.w = f2bf(v.w);
            *(us4*)(&As[row][j * 4]) = u;
        }
        if constexpr (MM_BBF[MODE]) {
            int n = t >> 2, j = t & 3;
            *(int4*)(&Bs[n][j * 8]) = *(const int4*)((const us*)Bv + (long)(n0 + n) * LDB + k0 + j * 8);
        } else {
            #pragma unroll
            for (int it = 0; it < 2; ++it) {
                int idx = t + it * 256;
                int n = idx >> 3, j = idx & 7;
                int gk = k0 + j * 4;
                float4 v = make_float4(0.f, 0.f, 0.f, 0.f);
                if ((N == 512 || n0 + n < N) && gk < K)
                    v = *(const float4*)((const float*)Bv + (long)(n0 + n) * LDB + gk);
                us4 u; u.x = f2bf(v.x); u.y = f2bf(v.y); u.z = f2bf(v.z); u.w = f2bf(v.w);
                *(us4*)(&Bs[n][j * 4]) = u;
            }
        }
        __syncthreads();
        bf16x8 a[4], bb[2];
        #pragma unroll
        for (int rt = 0; rt < 4; ++rt) a[rt] = *(const bf16x8*)(&As[wm * 64 + rt * 16 + m16][q * 8]);
        #pragma unroll
        for (int ct = 0; ct < 2; ++ct) bb[ct] = *(const bf16x8*)(&Bs[wn * 32 + ct * 16 + m16][q * 8]);
        #pragma unroll
        for (int rt = 0; rt < 4; ++rt)
            #pragma unroll
            for (int ct = 0; ct < 2; ++ct)
                acc[rt][ct] = __builtin_amdgcn_mfma_f32_16x16x32_bf16(a[rt], bb[ct], acc[rt][ct], 0, 0, 0);
        __syncthreads();
    }
    #pragma unroll
    for (int rt = 0; rt < 4; ++rt) {
        #pragma unroll
        for (int ct = 0; ct < 2; ++ct) {
            int col = n0 + wn * 32 + ct * 16 + m16;
            if (N != 512 && col >= N) continue;
            #pragma unroll
            for (int r = 0; r < 4; ++r) {
                int row = wm * 64 + rt * 16 + q * 4 + r;
                float v = acc[rt][ct][r];
                if constexpr (MODE == 0) {
                    v += bias[col]; v = v > 0.f ? v : 0.1f * v;
                    Cf[(long)row * 300 + col] = v;
                } else if constexpr (MODE == 1) {
                    Cf[(long)row * 300 + col] = v + bias[col];
                } else if constexpr (MODE == 2 || MODE == 6) {
                    Cf[(long)row * 512 + col] = v;
                } else if constexpr (MODE == 3) {
                    Cb[(long)row * 840 + col] = f2bf(gate[(row >> 4) * FEAT + col] * v);
                } else if constexpr (MODE == 4) {
                    Cf[(long)row * HLD + col] = gate[(row >> 4) * SEM + col] * v;
                } else if constexpr (MODE == 5) {
                    Cb[(long)row * 840 + 512 + col] = f2bf(v);
                } else if constexpr (MODE == 7) {
                    Cf[(long)row * 512 + col] = v + res[(long)row * 512 + col];
                }
            }
        }
    }
}

// =============== cconst[b,w] = psemT[b*16+w] . b2 ===============
__global__ void k_cconst(const float* __restrict__ psemT, const float* __restrict__ b2,
                         float* __restrict__ cconst) {
    int b = blockIdx.x, t = threadIdx.x;
    int w = t >> 4, l = t & 15;
    float a = 0.f;
    for (int s = l; s < SEM; s += 16) a += psemT[(long)(b * NWAY + w) * HLD + s] * b2[s];
    a += __shfl_xor(a, 1); a += __shfl_xor(a, 2);
    a += __shfl_xor(a, 4); a += __shfl_xor(a, 8);
    if (l == 0) cconst[b * NWAY + w] = a;
}

// =============== scores + fused per-block softmax partials (KB=64 stages) ===============
__global__ __launch_bounds__(256) void k_scores_mfma(const us* __restrict__ bwh,
        const us* __restrict__ h, const us* __restrict__ pqt,
        const float* __restrict__ cconst, float* __restrict__ scores,
        float* __restrict__ pmax, float* __restrict__ psum) {
    __shared__ us As[128][72];       // [m][64k] +8 pad
    __shared__ us Bs[NWAY][840];
    __shared__ float sred[4][16];
    const int b = blockIdx.y;
    const int bm = blockIdx.x * 128;
    const int t = threadIdx.x;
    const int wv = t >> 6, lane = t & 63;
    const int m16 = lane & 15, q = lane >> 4;
    for (int c = t; c < NWAY * 105; c += 256) {
        int n = c / 105, j = c % 105;
        *(int4*)(&Bs[n][j * 8]) = *(const int4*)(pqt + ((long)b * NWAY + n) * 840 + j * 8);
    }
    f32x4 acc[2];
    acc[0] = (f32x4){0,0,0,0};
    acc[1] = (f32x4){0,0,0,0};
    for (int ks = 0; ks < 13; ++ks) {
        int k0 = ks * 64;
        #pragma unroll
        for (int it = 0; it < 4; ++it) {  // A: 128 rows x 8 us8 groups, 4 loads in flight
            int c = t + it * 256;
            int row = c >> 3, j = c & 7;
            int gm = bm + row, gk = k0 + j * 8;
            us8 u = (us8){0, 0, 0, 0, 0, 0, 0, 0};
            if (gk < FEAT)      u = *(const us8*)(bwh + ((long)b * NBASE + gm) * FEAT + gk);
            else if (gk < CAT)  u = *(const us8*)(h + ((long)b * NBASE + gm) * HLD + (gk - FEAT));
            *(us8*)(&As[row][j * 8]) = u;
        }
        __syncthreads();
        #pragma unroll
        for (int kc = 0; kc < 64; kc += 32) {
            bf16x8 bb = *(const bf16x8*)(&Bs[m16][k0 + kc + q * 8]);
            #pragma unroll
            for (int rt = 0; rt < 2; ++rt) {
                bf16x8 a = *(const bf16x8*)(&As[wv * 32 + rt * 16 + m16][kc + q * 8]);
                acc[rt] = __builtin_amdgcn_mfma_f32_16x16x32_bf16(a, bb, acc[rt], 0, 0, 0);
            }
        }
        __syncthreads();
    }
    const float invT = 0.04419417382415922f;  // 1/sqrt(512)
    float cadd = cconst[b * NWAY + m16];
    float vals[8];
    #pragma unroll
    for (int rt = 0; rt < 2; ++rt) {
        int nrow = bm + wv * 32 + rt * 16 + q * 4;
        #pragma unroll
        for (int r = 0; r < 4; ++r) {
            float v = (nrow + r < NBASE) ? (acc[rt][r] + cadd) * invT : -1e30f;
            vals[rt * 4 + r] = v;
        }
        if (nrow + 3 < NBASE) {
            float4 st = make_float4(vals[rt * 4], vals[rt * 4 + 1], vals[rt * 4 + 2], vals[rt * 4 + 3]);
            *(float4*)(scores + ((long)b * NWAY + m16) * NBASE + nrow) = st;
        } else {
            for (int r = 0; r < 4; ++r)
                if (nrow + r < NBASE)
                    scores[((long)b * NWAY + m16) * NBASE + nrow + r] = vals[rt * 4 + r];
        }
    }
    float lm = vals[0];
    #pragma unroll
    for (int i = 1; i < 8; ++i) lm = fmaxf(lm, vals[i]);
    lm = fmaxf(lm, __shfl_xor(lm, 16));
    lm = fmaxf(lm, __shfl_xor(lm, 32));
    if (q == 0) sred[wv][m16] = lm;
    __syncthreads();
    float bmax = fmaxf(fmaxf(sred[0][m16], sred[1][m16]), fmaxf(sred[2][m16], sred[3][m16]));
    __syncthreads();
    float ls = 0.f;
    #pragma unroll
    for (int i = 0; i < 8; ++i) ls += __expf(vals[i] - bmax);
    ls += __shfl_xor(ls, 16);
    ls += __shfl_xor(ls, 32);
    if (q == 0) sred[wv][m16] = ls;
    __syncthreads();
    if (wv == 0 && lane < 16) {
        float tot = sred[0][m16] + sred[1][m16] + sred[2][m16] + sred[3][m16];
        pmax[((long)b * NWAY + m16) * 63 + blockIdx.x] = bmax;
        psum[((long)b * NWAY + m16) * 63 + blockIdx.x] = tot;
    }
}

// =============== combine partials -> row max & 1/sum ===============
__global__ void k_combine(const float* __restrict__ pmax, const float* __restrict__ psum,
                          float* __restrict__ rmax, float* __restrict__ rinv) {
    int b = blockIdx.x, t = threadIdx.x;
    int w = t >> 4, l = t & 15;
    long base = ((long)b * NWAY + w) * 63;
    float m = -1e30f;
    for (int i = l; i < 63; i += 16) m = fmaxf(m, pmax[base + i]);
    m = fmaxf(m, __shfl_xor(m, 1)); m = fmaxf(m, __shfl_xor(m, 2));
    m = fmaxf(m, __shfl_xor(m, 4)); m = fmaxf(m, __shfl_xor(m, 8));
    float s = 0.f;
    for (int i = l; i < 63; i += 16) s += psum[base + i] * __expf(pmax[base + i] - m);
    s += __shfl_xor(s, 1); s += __shfl_xor(s, 2);
    s += __shfl_xor(s, 4); s += __shfl_xor(s, 8);
    if (l == 0) { rmax[b * NWAY + w] = m; rinv[b * NWAY + w] = 1.0f / s; }
}

// =============== ov = softmax(scores) @ bwh, exp fused, unroll-8 MLP ===============
__global__ void k_ov(const float* __restrict__ scores, const float* __restrict__ rmax,
                     const float* __restrict__ rinv, const us* __restrict__ bwh,
                     float* __restrict__ ov) {
    int b = blockIdx.x, ch = blockIdx.y;  // 50 chunks of 160 rows
    int t = threadIdx.x;
    __shared__ float pr[NWAY][160];
    for (int i = t; i < NWAY * 160; i += 256) {
        int w = i / 160, j = i % 160;
        float sc = scores[((long)b * NWAY + w) * NBASE + (long)ch * 160 + j];
        pr[w][j] = __expf(sc - rmax[b * NWAY + w]) * rinv[b * NWAY + w];
    }
    __syncthreads();
    float a0[NWAY], a1[NWAY];
    #pragma unroll
    for (int w = 0; w < NWAY; ++w) { a0[w] = 0.f; a1[w] = 0.f; }
    const us* bp = bwh + ((long)b * NBASE + (long)ch * 160) * FEAT + 2 * t;
    for (int j0 = 0; j0 < 160; j0 += 8) {
        us2 u[8];
        #pragma unroll
        for (int uu = 0; uu < 8; ++uu)
            u[uu] = *(const us2*)(bp + (long)(j0 + uu) * FEAT);
        #pragma unroll
        for (int uu = 0; uu < 8; ++uu) {
            float v0 = bf2f(u[uu].x), v1 = bf2f(u[uu].y);
            #pragma unroll
            for (int w = 0; w < NWAY; ++w) {
                a0[w] += pr[w][j0 + uu] * v0;
                a1[w] += pr[w][j0 + uu] * v1;
            }
        }
    }
    for (int w = 0; w < NWAY; ++w) {
        atomicAdd(&ov[((long)b * NWAY + w) * FEAT + 2 * t], a0[w]);
        atomicAdd(&ov[((long)b * NWAY + w) * FEAT + 2 * t + 1], a1[w]);
    }
}

extern "C" void kernel_launch(void* const* d_in, const int* in_sizes, int n_in,
                              void* d_out, int out_size, void* d_ws, size_t ws_size,
                              hipStream_t stream) {
    (void)in_sizes; (void)n_in; (void)out_size; (void)ws_size;
    const float* sf   = (const float*)d_in[0];
    const float* bw   = (const float*)d_in[1];
    const float* ssm  = (const float*)d_in[2];
    const float* bsm  = (const float*)d_in[3];
    const float* mw1  = (const float*)d_in[4];
    const float* mb1  = (const float*)d_in[5];
    const float* mw2  = (const float*)d_in[6];
    const float* mb2  = (const float*)d_in[7];
    const float* vfw  = (const float*)d_in[8];
    const float* vfb  = (const float*)d_in[9];
    const float* sfw  = (const float*)d_in[10];
    const float* sfb  = (const float*)d_in[11];
    const float* wqs  = (const float*)d_in[12];
    const float* wks  = (const float*)d_in[13];
    const float* wvs  = (const float*)d_in[14];
    const float* wqss = (const float*)d_in[15];
    const float* wkss = (const float*)d_in[16];
    const float* fcw  = (const float*)d_in[17];

    float* out = (float*)d_out;
    float* scores = out + NB * NWAY * FEAT;  // d_out = [out | attn_score]

    char* wsb = (char*)d_ws;
    us* bwh    = (us*)(wsb + O_BWH);
    us* h      = (us*)(wsb + O_H);
    us* w1t    = (us*)(wsb + O_W1T);
    us* w2t    = (us*)(wsb + O_W2T);
    us* qwT    = (us*)(wsb + O_QWT);
    us* wvsT   = (us*)(wsb + O_WVST);
    us* fcwT   = (us*)(wsb + O_FCWT);
    us* pqt    = (us*)(wsb + O_PQT);
    float* pmax   = (float*)(wsb + O_PMAX);
    float* psum   = (float*)(wsb + O_PSUM);
    float* rmax   = (float*)(wsb + O_RMAX);
    float* rinv   = (float*)(wsb + O_RINV);
    float* mbw    = (float*)(wsb + O_MBW);
    float* mh     = (float*)(wsb + O_MH);
    float* gv     = (float*)(wsb + O_GV);
    float* gs     = (float*)(wsb + O_GS);
    float* avgv   = (float*)(wsb + O_AVG);
    float* psemT  = (float*)(wsb + O_PSEMT);
    float* sscH   = (float*)(wsb + O_SSCH);
    float* ssc    = (float*)(wsb + O_SSC);
    float* qtot   = (float*)(wsb + O_QTOT);
    float* cconst = (float*)(wsb + O_CC);
    float* tmp    = (float*)(wsb + O_TMP);
    float* ov     = (float*)(wsb + O_OV);

    hipMemsetAsync(mbw, 0, (NB * FEAT + NB * SEM) * sizeof(float), stream);  // mbw+mh
    hipMemsetAsync(pqt, 0, (long)NB * NWAY * 840 * 2, stream);               // zero pads

    k_prep<<<dim3(1664, 5), 256, 0, stream>>>(mw1, mw2, wqs, wqss, wvs, fcw, w1t, w2t, qwT, wvsT, fcwT);
    k_cvt_bw<<<dim3(NB, 125), 256, 0, stream>>>(bw, bwh, mbw);
    k_hgemm_mfma<<<dim3(63, NB), 256, 0, stream>>>(bsm, w1t, mb1, h, mh);
    k_avg<<<dim3(6, NB), 256, 0, stream>>>(mbw, mh, mw2, mb2, avgv);
    k_gates_mv<<<dim3(13, NB), 256, 0, stream>>>(avgv, vfw, vfb, sfw, sfb, gv, gs);
    k_mm<0><<<5, 256, 0, stream>>>(ssm, nullptr, w1t, mb1, nullptr, nullptr, sscH, nullptr);
    k_mm<1><<<5, 256, 0, stream>>>(sscH, nullptr, w2t, mb2, nullptr, nullptr, ssc, nullptr);
    k_mm<2><<<8, 256, 0, stream>>>(sf, ssc, qwT, nullptr, nullptr, nullptr, qtot, nullptr);
    k_mm<3><<<8, 256, 0, stream>>>(qtot, nullptr, wks, nullptr, gv, nullptr, nullptr, pqt);
    k_mm<4><<<5, 256, 0, stream>>>(qtot, nullptr, wkss, nullptr, gs, nullptr, psemT, nullptr);
    k_mm<5><<<5, 256, 0, stream>>>(psemT, nullptr, mw2, nullptr, nullptr, nullptr, nullptr, pqt);
    k_cconst<<<NB, 256, 0, stream>>>(psemT, mb2, cconst);
    k_scores_mfma<<<dim3(63, NB), 256, 0, stream>>>(bwh, h, pqt, cconst, scores, pmax, psum);
    k_combine<<<NB, 256, 0, stream>>>(pmax, psum, rmax, rinv);
    hipMemsetAsync(ov, 0, NB * NWAY * FEAT * sizeof(float), stream);
    k_ov<<<dim3(NB, 50), 256, 0, stream>>>(scores, rmax, rinv, bwh, ov);
    k_mm<6><<<8, 256, 0, stream>>>(ov, nullptr, wvsT, nullptr, nullptr, nullptr, tmp, nullptr);
    k_mm<7><<<8, 256, 0, stream>>>(tmp, nullptr, fcwT, nullptr, nullptr, sf, out, nullptr);
}